// Round 17
// baseline (1923.066 us; speedup 1.0000x reference)
//
#include <hip/hip_runtime.h>
#include <hip/hip_bf16.h>
#include <math.h>

#define LQ 50
#define DD 200
#define NBLK 3
#define NT 1024
#define NW 16

#define KC 13          // k-chunks of 16 for 32x32 MFMA (208 >= 200)
#define NT32 7         // n-tiles of 32 (224 >= 200)
#define MAT_U (KC * NT32 * 128)  // s16x8 units per matrix

#define APS 408   // pair-buffer row stride (shorts)
#define VTS 66    // v_T row stride (shorts)
#define PS  136   // P row stride (shorts)
#define SS  66    // S row stride (floats)

#define NEGC (-4294967295.0f)
#define SCALE 0.07071067811865475f

typedef __attribute__((ext_vector_type(4)))  float f32x4;
typedef __attribute__((ext_vector_type(16))) float f32x16;
typedef __attribute__((ext_vector_type(8)))  short s16x8;

__device__ __forceinline__ unsigned short bf16_rne(float x) {
  unsigned u = __float_as_uint(x);
  unsigned r = u + 0x7FFF + ((u >> 16) & 1);
  return (unsigned short)(r >> 16);
}
__device__ __forceinline__ float bf16_f(unsigned short h) {
  return __uint_as_float((unsigned)h << 16);
}
__device__ __forceinline__ void splitf(float x, short& h, short& l) {
  __hip_bfloat16 bh = __float2bfloat16(x);
  float hf = __bfloat162float(bh);
  __hip_bfloat16 bl = __float2bfloat16(x - hf);
  h = (short)__builtin_bit_cast(unsigned short, bh);
  l = (short)__builtin_bit_cast(unsigned short, bl);
}
__device__ __forceinline__ unsigned short bfbits(float x) {
  __hip_bfloat16 bh = __float2bfloat16(x);
  return __builtin_bit_cast(unsigned short, bh);
}
__device__ __forceinline__ float joinf(short h, short l) {
  return __bfloat162float(__builtin_bit_cast(__hip_bfloat16, (unsigned short)h)) +
         __bfloat162float(__builtin_bit_cast(__hip_bfloat16, (unsigned short)l));
}

__device__ __forceinline__ float wave_sum(float v) {
  #pragma unroll
  for (int off = 32; off > 0; off >>= 1) v += __shfl_xor(v, off, 64);
  return v;
}
__device__ __forceinline__ float wave_max(float v) {
  #pragma unroll
  for (int off = 32; off > 0; off >>= 1) v = fmaxf(v, __shfl_xor(v, off, 64));
  return v;
}

// ---- pre-swizzle: W f32 [DD][DD] -> bf16 hi/lo fragments for 32x32x16 ----
__global__ __launch_bounds__(64)
void swizzle_w(const float* __restrict__ Wq, const float* __restrict__ Wk,
               const float* __restrict__ Wv, const float* __restrict__ W1,
               const float* __restrict__ W2, unsigned short* __restrict__ wbuf)
{
  int t = blockIdx.x;             // 15*KC*NT32
  int nt = t % NT32; t /= NT32;
  int kc = t % KC;  t /= KC;
  int mat = t;
  int layer = mat / 5, which = mat % 5;
  const float* W;
  switch (which) {
    case 0: W = Wq; break;
    case 1: W = Wk; break;
    case 2: W = Wv; break;
    case 3: W = W1; break;
    default: W = W2; break;
  }
  W += (size_t)layer * DD * DD;

  const int l = threadIdx.x;
  const int n = nt * 32 + (l & 31);
  const int kb = kc * 16 + (l >> 5) * 8;
  s16x8 vh, vl;
  #pragma unroll
  for (int j = 0; j < 8; ++j) {
    int k = kb + j;
    float w = (k < DD && n < DD) ? W[k * DD + n] : 0.0f;
    unsigned short h = bf16_rne(w);
    unsigned short lo = bf16_rne(w - bf16_f(h));
    vh[j] = (short)h;
    vl[j] = (short)lo;
  }
  size_t base = ((size_t)((mat * KC + kc) * NT32 + nt)) * 1024 + l * 8;
  *(s16x8*)(wbuf + base)       = vh;
  *(s16x8*)(wbuf + base + 512) = vl;
}

// ---- 32x32 single-tile C^T matmul (A=W, B=x pair), pair dst, relu, prefetch --
// Register shape identical to mm32_w1 (never spills at the 128-reg cap).
__device__ __forceinline__ void mm32_ct_single(
    const short* __restrict__ srcp, const s16x8* __restrict__ wt,
    const float* __restrict__ bias, short* __restrict__ dstp,
    int nt, int rt, int lane)
{
  const int h = lane >> 5, l31 = lane & 31;
  f32x16 acc = (f32x16)0.f;
  int r = rt * 32 + l31;
  int rr = (r >= LQ) ? 0 : r;
  const short* arow = srcp + rr * APS;

  const s16x8* wp = wt + (size_t)nt * 128 + lane;
  s16x8 wh = wp[0], wl = wp[64];
  #pragma unroll 1
  for (int kc = 0; kc < KC; ++kc) {
    s16x8 nh = (s16x8)0, nl = (s16x8)0;
    if (kc + 1 < KC) {
      const s16x8* np = wt + (size_t)((kc + 1) * NT32 + nt) * 128 + lane;
      nh = np[0]; nl = np[64];
    }
    const int ch = 2 * kc + h;
    s16x8 ah = (s16x8)0, al = (s16x8)0;
    if (ch < 25) { const short* p = arow + ch * 16; ah = *(const s16x8*)p; al = *(const s16x8*)(p + 8); }
    acc = __builtin_amdgcn_mfma_f32_32x32x16_bf16(wh, ah, acc, 0, 0, 0);
    acc = __builtin_amdgcn_mfma_f32_32x32x16_bf16(wh, al, acc, 0, 0, 0);
    acc = __builtin_amdgcn_mfma_f32_32x32x16_bf16(wl, ah, acc, 0, 0, 0);
    wh = nh; wl = nl;
  }

  if (r < LQ) {
    #pragma unroll
    for (int q2 = 0; q2 < 4; ++q2) {
      const int nb = nt * 32 + 8 * q2 + 4 * h;
      if (nb + 3 < DD) {
        float4 bv = *(const float4*)(bias + nb);
        float v0 = fmaxf(acc[q2*4+0] + bv.x, 0.f);
        float v1 = fmaxf(acc[q2*4+1] + bv.y, 0.f);
        float v2 = fmaxf(acc[q2*4+2] + bv.z, 0.f);
        float v3 = fmaxf(acc[q2*4+3] + bv.w, 0.f);
        short h0,l0,h1,l1,h2,l2,h3,l3;
        splitf(v0,h0,l0); splitf(v1,h1,l1); splitf(v2,h2,l2); splitf(v3,h3,l3);
        uint2 ph, pl;
        ph.x = (unsigned short)h0 | ((unsigned)(unsigned short)h1 << 16);
        ph.y = (unsigned short)h2 | ((unsigned)(unsigned short)h3 << 16);
        pl.x = (unsigned short)l0 | ((unsigned)(unsigned short)l1 << 16);
        pl.y = (unsigned short)l2 | ((unsigned)(unsigned short)l3 << 16);
        short* base = dstp + r * APS + (nb >> 3) * 16 + (nb & 7);
        *(uint2*)base = ph;
        *(uint2*)(base + 8) = pl;
      }
    }
  }
}

// ---- 32x32 single-tile V projection (A=x pair, B=W), hi-only V^T, prefetch --
__device__ __forceinline__ void mm32_v_single(
    const short* __restrict__ srcp, const s16x8* __restrict__ wt,
    const float* __restrict__ bias, short* __restrict__ vtp,
    int nt, int rt, int lane)
{
  const int h = lane >> 5, l31 = lane & 31;
  f32x16 acc = (f32x16)0.f;
  int r0 = rt * 32 + l31;
  int rr = (r0 >= LQ) ? 0 : r0;
  const short* arow = srcp + rr * APS;

  const s16x8* wp = wt + (size_t)nt * 128 + lane;
  s16x8 wh = wp[0], wl = wp[64];
  #pragma unroll 1
  for (int kc = 0; kc < KC; ++kc) {
    s16x8 nh = (s16x8)0, nl = (s16x8)0;
    if (kc + 1 < KC) {
      const s16x8* np = wt + (size_t)((kc + 1) * NT32 + nt) * 128 + lane;
      nh = np[0]; nl = np[64];
    }
    const int ch = 2 * kc + h;
    s16x8 ah = (s16x8)0, al = (s16x8)0;
    if (ch < 25) { const short* p = arow + ch * 16; ah = *(const s16x8*)p; al = *(const s16x8*)(p + 8); }
    acc = __builtin_amdgcn_mfma_f32_32x32x16_bf16(ah, wh, acc, 0, 0, 0);
    acc = __builtin_amdgcn_mfma_f32_32x32x16_bf16(al, wh, acc, 0, 0, 0);
    acc = __builtin_amdgcn_mfma_f32_32x32x16_bf16(ah, wl, acc, 0, 0, 0);
    wh = nh; wl = nl;
  }

  // C: lane holds col d = nt*32 + l31; rows rb = rt*32 + 8*q2 + 4*h (+e)
  const int d = nt * 32 + l31;
  if (d < DD) {
    const float bvs = bias[d];
    #pragma unroll
    for (int q2 = 0; q2 < 4; ++q2) {
      const int rb = rt * 32 + 8 * q2 + 4 * h;
      float vv[4];
      #pragma unroll
      for (int e = 0; e < 4; ++e) {
        const int r = rb + e;
        float v = acc[q2*4+e] + bvs;
        vv[e] = (r < LQ) ? fmaxf(v, 0.f) : 0.f;
      }
      uint2 pk;
      pk.x = (unsigned)bfbits(vv[0]) | ((unsigned)bfbits(vv[1]) << 16);
      pk.y = (unsigned)bfbits(vv[2]) | ((unsigned)bfbits(vv[3]) << 16);
      *(uint2*)(vtp + d * VTS + (rb >> 3) * 8 + (rb & 7)) = pk;
    }
  }
}

// ---- 32x32 W1: C^T, pair-src (3-term), HI-ONLY pair dst, relu, prefetch ----
__device__ __forceinline__ void mm32_w1(
    const short* __restrict__ srcp, const s16x8* __restrict__ wt,
    const float* __restrict__ bias, short* __restrict__ dstp,
    int nt, int rt, int lane)
{
  const int h = lane >> 5, l31 = lane & 31;
  f32x16 acc = (f32x16)0.f;
  int r = rt * 32 + l31;
  int rr = (r >= LQ) ? 0 : r;
  const short* arow = srcp + rr * APS;

  const s16x8* wp = wt + (size_t)nt * 128 + lane;
  s16x8 wh = wp[0], wl = wp[64];
  #pragma unroll 1
  for (int kc = 0; kc < KC; ++kc) {
    s16x8 nh = (s16x8)0, nl = (s16x8)0;
    if (kc + 1 < KC) {
      const s16x8* np = wt + (size_t)((kc + 1) * NT32 + nt) * 128 + lane;
      nh = np[0]; nl = np[64];
    }
    const int ch = 2 * kc + h;
    s16x8 ah = (s16x8)0, al = (s16x8)0;
    if (ch < 25) { const short* p = arow + ch * 16; ah = *(const s16x8*)p; al = *(const s16x8*)(p + 8); }
    acc = __builtin_amdgcn_mfma_f32_32x32x16_bf16(wh, ah, acc, 0, 0, 0);
    acc = __builtin_amdgcn_mfma_f32_32x32x16_bf16(wh, al, acc, 0, 0, 0);
    acc = __builtin_amdgcn_mfma_f32_32x32x16_bf16(wl, ah, acc, 0, 0, 0);
    wh = nh; wl = nl;
  }

  if (r < LQ) {
    #pragma unroll
    for (int q2 = 0; q2 < 4; ++q2) {
      const int nb = nt * 32 + 8 * q2 + 4 * h;
      if (nb + 3 < DD) {
        float4 bv = *(const float4*)(bias + nb);
        float v0 = fmaxf(acc[q2*4+0] + bv.x, 0.f);
        float v1 = fmaxf(acc[q2*4+1] + bv.y, 0.f);
        float v2 = fmaxf(acc[q2*4+2] + bv.z, 0.f);
        float v3 = fmaxf(acc[q2*4+3] + bv.w, 0.f);
        uint2 ph;
        ph.x = (unsigned)bfbits(v0) | ((unsigned)bfbits(v1) << 16);
        ph.y = (unsigned)bfbits(v2) | ((unsigned)bfbits(v3) << 16);
        *(uint2*)(dstp + r * APS + (nb >> 3) * 16 + (nb & 7)) = ph;   // hi only
      }
    }
  }
}

// ---- 32x32 W2: C^T, HI-only src (2-term), f32 dst, no relu, prefetch ----
__device__ __forceinline__ void mm32_w2(
    const short* __restrict__ srcp, const s16x8* __restrict__ wt,
    const float* __restrict__ bias, float* __restrict__ dstf,
    int nt, int rt, int lane)
{
  const int h = lane >> 5, l31 = lane & 31;
  f32x16 acc = (f32x16)0.f;
  int r = rt * 32 + l31;
  int rr = (r >= LQ) ? 0 : r;
  const short* arow = srcp + rr * APS;

  const s16x8* wp = wt + (size_t)nt * 128 + lane;
  s16x8 wh = wp[0], wl = wp[64];
  #pragma unroll 1
  for (int kc = 0; kc < KC; ++kc) {
    s16x8 nh = (s16x8)0, nl = (s16x8)0;
    if (kc + 1 < KC) {
      const s16x8* np = wt + (size_t)((kc + 1) * NT32 + nt) * 128 + lane;
      nh = np[0]; nl = np[64];
    }
    const int ch = 2 * kc + h;
    s16x8 ah = (s16x8)0;
    if (ch < 25) ah = *(const s16x8*)(arow + ch * 16);   // hi only
    acc = __builtin_amdgcn_mfma_f32_32x32x16_bf16(wh, ah, acc, 0, 0, 0);
    acc = __builtin_amdgcn_mfma_f32_32x32x16_bf16(wl, ah, acc, 0, 0, 0);
    wh = nh; wl = nl;
  }

  if (r < LQ) {
    #pragma unroll
    for (int q2 = 0; q2 < 4; ++q2) {
      const int d0 = nt * 32 + 8 * q2 + 4 * h;
      if (d0 + 3 < DD) {
        float4 bv = *(const float4*)(bias + d0);
        float4 w4;
        w4.x = acc[q2*4+0] + bv.x; w4.y = acc[q2*4+1] + bv.y;
        w4.z = acc[q2*4+2] + bv.z; w4.w = acc[q2*4+3] + bv.w;
        *(float4*)(dstf + r * DD + d0) = w4;
      }
    }
  }
}

__global__ __launch_bounds__(NT)
void transformer_kernel(const int* __restrict__ tokens,
                        const float* __restrict__ emb,
                        const unsigned short* __restrict__ wbuf,
                        const float* __restrict__ bq, const float* __restrict__ bk,
                        const float* __restrict__ bv, const float* __restrict__ b1,
                        const float* __restrict__ b2,
                        const float* __restrict__ lng, const float* __restrict__ lnb,
                        float* __restrict__ out)
{
  __shared__ __align__(16) short xs_p[LQ * APS];
  __shared__ __align__(16) short q_p [LQ * APS];
  __shared__ __align__(16) short k_p [LQ * APS];
  __shared__ __align__(16) short vt_p[DD * VTS];
  __shared__ float rowsum[52];

  float* Sf  = (float*)q_p;          // S f32 [50][66]  (in q_p after Q dead)
  short* Pp  = q_p + 8192;           // P hi-only [50][PS]
  float* h2f = (float*)k_p;          // h2 f32 [50][200]

  const int b    = blockIdx.x;
  const int tid  = threadIdx.x;
  const int lane = tid & 63;
  const int wv   = tid >> 6;
  const int g    = lane >> 4, c = lane & 15;   // 16x16 frag coords

  // ---- embedding gather -> xs pair
  for (int o = tid; o < LQ * 25; o += NT) {
    int r = o / 25, ch = o % 25;
    int tok = tokens[b * LQ + r];
    const float* ep = emb + (size_t)tok * DD + ch * 8;
    float4 a0 = *(const float4*)ep;
    float4 a1 = *(const float4*)(ep + 4);
    float xv[8] = {a0.x, a0.y, a0.z, a0.w, a1.x, a1.y, a1.z, a1.w};
    s16x8 hh, ll;
    #pragma unroll
    for (int j = 0; j < 8; ++j) { short h, l; splitf(xv[j], h, l); hh[j] = h; ll[j] = l; }
    short* dp = xs_p + r * APS + ch * 16;
    *(s16x8*)dp = hh;
    *(s16x8*)(dp + 8) = ll;
  }
  __syncthreads();

  for (int layer = 0; layer < NBLK; ++layer) {
    const s16x8* wq  = (const s16x8*)wbuf + (size_t)(layer * 5 + 0) * MAT_U;
    const s16x8* wk  = (const s16x8*)wbuf + (size_t)(layer * 5 + 1) * MAT_U;
    const s16x8* wvv = (const s16x8*)wbuf + (size_t)(layer * 5 + 2) * MAT_U;
    const s16x8* w1  = (const s16x8*)wbuf + (size_t)(layer * 5 + 3) * MAT_U;
    const s16x8* w2  = (const s16x8*)wbuf + (size_t)(layer * 5 + 4) * MAT_U;
    const float* bql = bq + layer * DD;
    const float* bkl = bk + layer * DD;
    const float* bvl = bv + layer * DD;
    const float* b1l = b1 + layer * DD;
    const float* b2l = b2 + layer * DD;
    const float* gl  = lng + layer * DD;
    const float* bl  = lnb + layer * DD;

    if (layer == 0) {
      for (int r = wv; r < LQ; r += NW) {
        float s = 0.f;
        #pragma unroll
        for (int t = 0; t < 4; ++t) {
          int cc = lane + 64 * t;
          if (cc < DD) {
            const short* p = xs_p + r * APS + (cc >> 3) * 16 + (cc & 7);
            s += joinf(p[0], p[8]);
          }
        }
        s = wave_sum(s);
        if (lane == 0) rowsum[r] = s;
      }
    }

    // ---- phase 2: Q + K as 28 single-acc tiles over all 16 waves
    for (int t = wv; t < 28; t += NW) {
      const int tt = (t < 14) ? t : (t - 14);
      const int nt = tt >> 1, rt = tt & 1;
      if (t < 14) mm32_ct_single(xs_p, wq, bql, q_p, nt, rt, lane);
      else        mm32_ct_single(xs_p, wk, bkl, k_p, nt, rt, lane);
    }
    __syncthreads();

    // ---- phase 3: QK^T (waves 8-15)  ||  V as 14 single-acc tiles (waves 0-7)
    f32x4 s0 = (f32x4)0.f, s1 = (f32x4)0.f;
    if (wv >= 8) {
      const int w8 = wv - 8;
      const int mt = w8 >> 1;
      const int nk0 = (w8 & 1) * 2;
      int qr = mt * 16 + c;          if (qr >= LQ) qr = 0;
      int kj0 = nk0 * 16 + c;        if (kj0 >= LQ) kj0 = 0;
      int kj1 = (nk0 + 1) * 16 + c;  if (kj1 >= LQ) kj1 = 0;
      const short* qrow = q_p + qr * APS;
      const short* k0r  = k_p + kj0 * APS;
      const short* k1r  = k_p + kj1 * APS;
      #pragma unroll 1
      for (int kt = 0; kt < 7; ++kt) {
        const int ch = kt * 4 + g;
        s16x8 qh = (s16x8)0, ql = (s16x8)0;
        s16x8 kh0 = (s16x8)0, kl0 = (s16x8)0, kh1 = (s16x8)0, kl1 = (s16x8)0;
        if (ch < 25) {
          qh  = *(const s16x8*)(qrow + ch * 16); ql  = *(const s16x8*)(qrow + ch * 16 + 8);
          kh0 = *(const s16x8*)(k0r + ch * 16);  kl0 = *(const s16x8*)(k0r + ch * 16 + 8);
          kh1 = *(const s16x8*)(k1r + ch * 16);  kl1 = *(const s16x8*)(k1r + ch * 16 + 8);
        }
        s0 = __builtin_amdgcn_mfma_f32_16x16x32_bf16(qh, kh0, s0, 0, 0, 0);
        s0 = __builtin_amdgcn_mfma_f32_16x16x32_bf16(ql, kh0, s0, 0, 0, 0);
        s0 = __builtin_amdgcn_mfma_f32_16x16x32_bf16(qh, kl0, s0, 0, 0, 0);
        s1 = __builtin_amdgcn_mfma_f32_16x16x32_bf16(qh, kh1, s1, 0, 0, 0);
        s1 = __builtin_amdgcn_mfma_f32_16x16x32_bf16(ql, kh1, s1, 0, 0, 0);
        s1 = __builtin_amdgcn_mfma_f32_16x16x32_bf16(qh, kl1, s1, 0, 0, 0);
      }
    } else {
      for (int t = wv; t < 14; t += 8)
        mm32_v_single(xs_p, wvv, bvl, vt_p, t >> 1, t & 1, lane);
    }
    __syncthreads();   // all q_p reads done -> S may overwrite

    // ---- phase 4: write S (scaled + key-masked) into Sf
    if (wv >= 8) {
      const int w8 = wv - 8;
      const int mt = w8 >> 1;
      const int nk0 = (w8 & 1) * 2;
      #pragma unroll
      for (int t = 0; t < 2; ++t) {
        const int j = (nk0 + t) * 16 + c;
        const f32x4 sa = t ? s1 : s0;
        const bool km = (j < LQ) && (rowsum[j] != 0.0f);
        #pragma unroll
        for (int q = 0; q < 4; ++q) {
          const int qi = mt * 16 + g * 4 + q;
          if (qi < LQ) Sf[qi * SS + j] = km ? sa[q] * SCALE : NEGC;
        }
      }
    }
    __syncthreads();

    // ---- phase 5: softmax rows -> P (hi only)
    for (int r = wv; r < LQ; r += NW) {
      float sm = -INFINITY;
      if (lane < LQ) sm = Sf[r * SS + lane];
      float m = wave_max(sm);
      float e = (lane < LQ) ? __expf(sm - m) : 0.0f;
      float ssum = wave_sum(e);
      float qm = (rowsum[r] == 0.0f) ? 0.0f : 1.0f;
      float a = e / ssum * qm;
      Pp[r * PS + (lane >> 3) * 16 + (lane & 7)] = (short)bfbits(a);
    }
    __syncthreads();

    // ---- phase 6: out^T = V^T @ P^T (P hi-only); residual RMW into xs pair
    if (wv < 13) {
      const int mt = wv;
      f32x4 pa[4];
      #pragma unroll
      for (int nq = 0; nq < 4; ++nq) pa[nq] = (f32x4)0.f;
      int vr = mt * 16 + c; if (vr >= DD) vr = 0;
      const short* vrow = vt_p + vr * VTS;
      #pragma unroll
      for (int kt = 0; kt < 2; ++kt) {
        s16x8 vh = *(const s16x8*)(vrow + (kt * 4 + g) * 8);
        #pragma unroll
        for (int nq = 0; nq < 4; ++nq) {
          int pr = nq * 16 + c; if (pr >= LQ) pr = 0;
          s16x8 pbh = *(const s16x8*)(Pp + pr * PS + (kt * 4 + g) * 16);
          pa[nq] = __builtin_amdgcn_mfma_f32_16x16x32_bf16(vh, pbh, pa[nq], 0, 0, 0);
        }
      }
      const int d0 = mt * 16 + g * 4;
      if (d0 + 3 < DD) {
        #pragma unroll
        for (int nq = 0; nq < 4; ++nq) {
          const int qq = nq * 16 + c;
          if (qq < LQ) {
            short* base = xs_p + qq * APS + (d0 >> 3) * 16 + (d0 & 7);
            uint2 ph = *(const uint2*)base;
            uint2 pl = *(const uint2*)(base + 8);
            float f0 = joinf((short)(ph.x & 0xFFFF), (short)(pl.x & 0xFFFF)) + pa[nq][0];
            float f1 = joinf((short)(ph.x >> 16),    (short)(pl.x >> 16))    + pa[nq][1];
            float f2 = joinf((short)(ph.y & 0xFFFF), (short)(pl.y & 0xFFFF)) + pa[nq][2];
            float f3 = joinf((short)(ph.y >> 16),    (short)(pl.y >> 16))    + pa[nq][3];
            short h0,l0,h1,l1,h2,l2,h3,l3;
            splitf(f0,h0,l0); splitf(f1,h1,l1); splitf(f2,h2,l2); splitf(f3,h3,l3);
            ph.x = (unsigned short)h0 | ((unsigned)(unsigned short)h1 << 16);
            ph.y = (unsigned short)h2 | ((unsigned)(unsigned short)h3 << 16);
            pl.x = (unsigned short)l0 | ((unsigned)(unsigned short)l1 << 16);
            pl.y = (unsigned short)l2 | ((unsigned)(unsigned short)l3 << 16);
            *(uint2*)base = ph;
            *(uint2*)(base + 8) = pl;
          }
        }
      }
    }
    __syncthreads();

    // ---- phase 7: W1 -> h1 (hi-only) in q_p  (14 waves)
    if (wv < 14) mm32_w1(xs_p, w1, b1l, q_p, wv >> 1, wv & 1, lane);
    __syncthreads();
    // ---- phase 8: W2 -> h2 f32 in k_p  (14 waves, h1 hi-only src)
    if (wv < 14) mm32_w2(q_p, w2, b2l, h2f, wv >> 1, wv & 1, lane);
    __syncthreads();

    // ---- phase 9: LayerNorm + residual -> xs pair; next-layer rowsum
    for (int r = wv; r < LQ; r += NW) {
      float hv[4];
      #pragma unroll
      for (int t = 0; t < 4; ++t) {
        int cc = lane + 64 * t;
        hv[t] = (cc < DD) ? h2f[r * DD + cc] : 0.f;
      }
      float mu = wave_sum(hv[0] + hv[1] + hv[2] + hv[3]) * (1.0f / 200.0f);
      float d0 = hv[0] - mu, d1 = hv[1] - mu, d2 = hv[2] - mu;
      float d3 = (lane + 192 < DD) ? (hv[3] - mu) : 0.f;
      float var = wave_sum(d0 * d0 + d1 * d1 + d2 * d2 + d3 * d3) * (1.0f / 200.0f);
      float inv = 1.0f / sqrtf(var + 1e-8f);
      float dd4[4] = {d0, d1, d2, d3};
      float rs = 0.f;
      #pragma unroll
      for (int t = 0; t < 4; ++t) {
        int cc = lane + 64 * t;
        if (cc < DD) {
          short* hp = xs_p + r * APS + (cc >> 3) * 16 + (cc & 7);
          float nv = dd4[t] * inv * gl[cc] + bl[cc] + joinf(hp[0], hp[8]);
          rs += nv;
          short h, l; splitf(nv, h, l);
          hp[0] = h; hp[8] = l;
        }
      }
      rs = wave_sum(rs);
      if (lane == 0) rowsum[r] = rs;
    }
    __syncthreads();
  }

  // ---- write result
  for (int o = tid; o < LQ * 25; o += NT) {
    int r = o / 25, ch = o % 25;
    const short* sp = xs_p + r * APS + ch * 16;
    s16x8 hh = *(const s16x8*)sp;
    s16x8 ll = *(const s16x8*)(sp + 8);
    float4 o0, o1;
    o0.x = joinf(hh[0], ll[0]); o0.y = joinf(hh[1], ll[1]);
    o0.z = joinf(hh[2], ll[2]); o0.w = joinf(hh[3], ll[3]);
    o1.x = joinf(hh[4], ll[4]); o1.y = joinf(hh[5], ll[5]);
    o1.z = joinf(hh[6], ll[6]); o1.w = joinf(hh[7], ll[7]);
    float* op = out + ((size_t)b * LQ + r) * DD + ch * 8;
    *(float4*)op = o0;
    *(float4*)(op + 4) = o1;
  }
}

extern "C" void kernel_launch(void* const* d_in, const int* in_sizes, int n_in,
                              void* d_out, int out_size, void* d_ws, size_t ws_size,
                              hipStream_t stream) {
  const int*   tokens = (const int*)  d_in[0];
  const float* emb    = (const float*)d_in[1];
  const float* Wq     = (const float*)d_in[2];
  const float* bq     = (const float*)d_in[3];
  const float* Wk     = (const float*)d_in[4];
  const float* bk     = (const float*)d_in[5];
  const float* Wv     = (const float*)d_in[6];
  const float* bv     = (const float*)d_in[7];
  const float* W1     = (const float*)d_in[8];
  const float* b1     = (const float*)d_in[9];
  const float* W2     = (const float*)d_in[10];
  const float* b2     = (const float*)d_in[11];
  const float* lng    = (const float*)d_in[12];
  const float* lnb    = (const float*)d_in[13];
  float* out = (float*)d_out;
  unsigned short* wbuf = (unsigned short*)d_ws;

  hipLaunchKernelGGL(swizzle_w, dim3(15 * KC * NT32), dim3(64), 0, stream,
                     Wq, Wk, Wv, W1, W2, wbuf);

  const int B = in_sizes[0] / LQ;   // 4096
  hipLaunchKernelGGL(transformer_kernel, dim3(B), dim3(NT), 0, stream,
                     tokens, emb, wbuf, bq, bk, bv, b1, b2, lng, lnb, out);
}

// Round 18
// 1757.612 us; speedup vs baseline: 1.0941x; 1.0941x over previous
//
#include <hip/hip_runtime.h>
#include <hip/hip_bf16.h>
#include <math.h>

#define LQ 50
#define DD 200
#define NBLK 3
#define NT 1024
#define NW 16

#define KC 13          // k-chunks of 16 for 32x32 MFMA (208 >= 200)
#define NT32 7         // n-tiles of 32 (224 >= 200)
#define MAT_U (KC * NT32 * 128)  // s16x8 units per matrix

#define APS 408   // pair-buffer row stride (shorts)
#define VTS 66    // v_T row stride (shorts)
#define PS  136   // P row stride (shorts)
#define SS  66    // S row stride (floats)

#define NEGC (-4294967295.0f)
#define SCALE 0.07071067811865475f

typedef __attribute__((ext_vector_type(4)))  float f32x4;
typedef __attribute__((ext_vector_type(16))) float f32x16;
typedef __attribute__((ext_vector_type(8)))  short s16x8;

__device__ __forceinline__ unsigned short bf16_rne(float x) {
  unsigned u = __float_as_uint(x);
  unsigned r = u + 0x7FFF + ((u >> 16) & 1);
  return (unsigned short)(r >> 16);
}
__device__ __forceinline__ float bf16_f(unsigned short h) {
  return __uint_as_float((unsigned)h << 16);
}
__device__ __forceinline__ void splitf(float x, short& h, short& l) {
  __hip_bfloat16 bh = __float2bfloat16(x);
  float hf = __bfloat162float(bh);
  __hip_bfloat16 bl = __float2bfloat16(x - hf);
  h = (short)__builtin_bit_cast(unsigned short, bh);
  l = (short)__builtin_bit_cast(unsigned short, bl);
}
__device__ __forceinline__ unsigned short bfbits(float x) {
  __hip_bfloat16 bh = __float2bfloat16(x);
  return __builtin_bit_cast(unsigned short, bh);
}
__device__ __forceinline__ float joinf(short h, short l) {
  return __bfloat162float(__builtin_bit_cast(__hip_bfloat16, (unsigned short)h)) +
         __bfloat162float(__builtin_bit_cast(__hip_bfloat16, (unsigned short)l));
}

__device__ __forceinline__ float wave_sum(float v) {
  #pragma unroll
  for (int off = 32; off > 0; off >>= 1) v += __shfl_xor(v, off, 64);
  return v;
}
__device__ __forceinline__ float wave_max(float v) {
  #pragma unroll
  for (int off = 32; off > 0; off >>= 1) v = fmaxf(v, __shfl_xor(v, off, 64));
  return v;
}

// ---- pre-swizzle: W f32 [DD][DD] -> bf16 hi/lo fragments for 32x32x16 ----
__global__ __launch_bounds__(64)
void swizzle_w(const float* __restrict__ Wq, const float* __restrict__ Wk,
               const float* __restrict__ Wv, const float* __restrict__ W1,
               const float* __restrict__ W2, unsigned short* __restrict__ wbuf)
{
  int t = blockIdx.x;             // 15*KC*NT32
  int nt = t % NT32; t /= NT32;
  int kc = t % KC;  t /= KC;
  int mat = t;
  int layer = mat / 5, which = mat % 5;
  const float* W;
  switch (which) {
    case 0: W = Wq; break;
    case 1: W = Wk; break;
    case 2: W = Wv; break;
    case 3: W = W1; break;
    default: W = W2; break;
  }
  W += (size_t)layer * DD * DD;

  const int l = threadIdx.x;
  const int n = nt * 32 + (l & 31);
  const int kb = kc * 16 + (l >> 5) * 8;
  s16x8 vh, vl;
  #pragma unroll
  for (int j = 0; j < 8; ++j) {
    int k = kb + j;
    float w = (k < DD && n < DD) ? W[k * DD + n] : 0.0f;
    unsigned short h = bf16_rne(w);
    unsigned short lo = bf16_rne(w - bf16_f(h));
    vh[j] = (short)h;
    vl[j] = (short)lo;
  }
  size_t base = ((size_t)((mat * KC + kc) * NT32 + nt)) * 1024 + l * 8;
  *(s16x8*)(wbuf + base)       = vh;
  *(s16x8*)(wbuf + base + 512) = vl;
}

// ---- 32x32 matmul, C^T (A=W, B=x pair), pair dst with relu. nt in 0..6 ----
__device__ __forceinline__ void mm32_ct_pair(
    const short* __restrict__ srcp, const s16x8* __restrict__ wt,
    const float* __restrict__ bias, short* __restrict__ dstp, int nt, int lane)
{
  const int h = lane >> 5, l31 = lane & 31;
  f32x16 acc0 = (f32x16)0.f, acc1 = (f32x16)0.f;
  int r1 = 32 + l31; if (r1 >= LQ) r1 = 0;
  const short* arow0 = srcp + l31 * APS;       // rows 0..31 all valid
  const short* arow1 = srcp + r1 * APS;

  #pragma unroll 1
  for (int kc = 0; kc < KC; ++kc) {
    const s16x8* wp = wt + (size_t)(kc * NT32 + nt) * 128 + lane;
    s16x8 wh = wp[0], wl = wp[64];
    const int ch = 2 * kc + h;
    const bool ok = (ch < 25);
    {
      s16x8 ah = (s16x8)0, al = (s16x8)0;
      if (ok) { const short* p = arow0 + ch * 16; ah = *(const s16x8*)p; al = *(const s16x8*)(p + 8); }
      __builtin_amdgcn_s_setprio(1);
      acc0 = __builtin_amdgcn_mfma_f32_32x32x16_bf16(wh, ah, acc0, 0, 0, 0);
      acc0 = __builtin_amdgcn_mfma_f32_32x32x16_bf16(wh, al, acc0, 0, 0, 0);
      acc0 = __builtin_amdgcn_mfma_f32_32x32x16_bf16(wl, ah, acc0, 0, 0, 0);
      __builtin_amdgcn_s_setprio(0);
    }
    {
      s16x8 ah = (s16x8)0, al = (s16x8)0;
      if (ok) { const short* p = arow1 + ch * 16; ah = *(const s16x8*)p; al = *(const s16x8*)(p + 8); }
      __builtin_amdgcn_s_setprio(1);
      acc1 = __builtin_amdgcn_mfma_f32_32x32x16_bf16(wh, ah, acc1, 0, 0, 0);
      acc1 = __builtin_amdgcn_mfma_f32_32x32x16_bf16(wh, al, acc1, 0, 0, 0);
      acc1 = __builtin_amdgcn_mfma_f32_32x32x16_bf16(wl, ah, acc1, 0, 0, 0);
      __builtin_amdgcn_s_setprio(0);
    }
  }

  // C^T: lane holds n_local = (reg&3)+8*(reg>>2)+4h for r = rt*32 + l31
  #pragma unroll
  for (int rt = 0; rt < 2; ++rt) {
    const int r = rt * 32 + l31;
    if (r < LQ) {
      #pragma unroll
      for (int q2 = 0; q2 < 4; ++q2) {
        const int nb = nt * 32 + 8 * q2 + 4 * h;
        if (nb + 3 < DD) {
          float4 bv = *(const float4*)(bias + nb);
          float v0 = fmaxf((rt ? acc1[q2*4+0] : acc0[q2*4+0]) + bv.x, 0.f);
          float v1 = fmaxf((rt ? acc1[q2*4+1] : acc0[q2*4+1]) + bv.y, 0.f);
          float v2 = fmaxf((rt ? acc1[q2*4+2] : acc0[q2*4+2]) + bv.z, 0.f);
          float v3 = fmaxf((rt ? acc1[q2*4+3] : acc0[q2*4+3]) + bv.w, 0.f);
          short h0,l0,h1,l1,h2,l2,h3,l3;
          splitf(v0,h0,l0); splitf(v1,h1,l1); splitf(v2,h2,l2); splitf(v3,h3,l3);
          uint2 ph, pl;
          ph.x = (unsigned short)h0 | ((unsigned)(unsigned short)h1 << 16);
          ph.y = (unsigned short)h2 | ((unsigned)(unsigned short)h3 << 16);
          pl.x = (unsigned short)l0 | ((unsigned)(unsigned short)l1 << 16);
          pl.y = (unsigned short)l2 | ((unsigned)(unsigned short)l3 << 16);
          short* base = dstp + r * APS + (nb >> 3) * 16 + (nb & 7);
          *(uint2*)base = ph;
          *(uint2*)(base + 8) = pl;
        }
      }
    }
  }
}

// ---- 32x32 V projection (A=x pair, B=W), hi-only transposed dst ----
__device__ __forceinline__ void mm32_v(
    const short* __restrict__ srcp, const s16x8* __restrict__ wt,
    const float* __restrict__ bias, short* __restrict__ vtp, int nt, int lane)
{
  const int h = lane >> 5, l31 = lane & 31;
  f32x16 acc0 = (f32x16)0.f, acc1 = (f32x16)0.f;
  int r1 = 32 + l31; if (r1 >= LQ) r1 = 0;
  const short* arow0 = srcp + l31 * APS;
  const short* arow1 = srcp + r1 * APS;

  #pragma unroll 1
  for (int kc = 0; kc < KC; ++kc) {
    const s16x8* wp = wt + (size_t)(kc * NT32 + nt) * 128 + lane;
    s16x8 wh = wp[0], wl = wp[64];
    const int ch = 2 * kc + h;
    const bool ok = (ch < 25);
    {
      s16x8 ah = (s16x8)0, al = (s16x8)0;
      if (ok) { const short* p = arow0 + ch * 16; ah = *(const s16x8*)p; al = *(const s16x8*)(p + 8); }
      __builtin_amdgcn_s_setprio(1);
      acc0 = __builtin_amdgcn_mfma_f32_32x32x16_bf16(ah, wh, acc0, 0, 0, 0);
      acc0 = __builtin_amdgcn_mfma_f32_32x32x16_bf16(al, wh, acc0, 0, 0, 0);
      acc0 = __builtin_amdgcn_mfma_f32_32x32x16_bf16(ah, wl, acc0, 0, 0, 0);
      __builtin_amdgcn_s_setprio(0);
    }
    {
      s16x8 ah = (s16x8)0, al = (s16x8)0;
      if (ok) { const short* p = arow1 + ch * 16; ah = *(const s16x8*)p; al = *(const s16x8*)(p + 8); }
      __builtin_amdgcn_s_setprio(1);
      acc1 = __builtin_amdgcn_mfma_f32_32x32x16_bf16(ah, wh, acc1, 0, 0, 0);
      acc1 = __builtin_amdgcn_mfma_f32_32x32x16_bf16(al, wh, acc1, 0, 0, 0);
      acc1 = __builtin_amdgcn_mfma_f32_32x32x16_bf16(ah, wl, acc1, 0, 0, 0);
      __builtin_amdgcn_s_setprio(0);
    }
  }

  const int d = nt * 32 + l31;
  if (d < DD) {
    const float bvs = bias[d];
    #pragma unroll
    for (int mt2 = 0; mt2 < 2; ++mt2) {
      #pragma unroll
      for (int q2 = 0; q2 < 4; ++q2) {
        const int rb = mt2 * 32 + 8 * q2 + 4 * h;
        float vv[4];
        #pragma unroll
        for (int e = 0; e < 4; ++e) {
          const int r = rb + e;
          float v = (mt2 ? acc1[q2*4+e] : acc0[q2*4+e]) + bvs;
          vv[e] = (r < LQ) ? fmaxf(v, 0.f) : 0.f;
        }
        uint2 pk;
        pk.x = (unsigned)bfbits(vv[0]) | ((unsigned)bfbits(vv[1]) << 16);
        pk.y = (unsigned)bfbits(vv[2]) | ((unsigned)bfbits(vv[3]) << 16);
        *(uint2*)(vtp + d * VTS + (rb >> 3) * 8 + (rb & 7)) = pk;
      }
    }
  }
}

// ---- 32x32 W1: C^T, pair-src (3-term), HI-ONLY pair dst, relu, prefetch ----
__device__ __forceinline__ void mm32_w1(
    const short* __restrict__ srcp, const s16x8* __restrict__ wt,
    const float* __restrict__ bias, short* __restrict__ dstp,
    int nt, int rt, int lane)
{
  const int h = lane >> 5, l31 = lane & 31;
  f32x16 acc = (f32x16)0.f;
  int r = rt * 32 + l31;
  int rr = (r >= LQ) ? 0 : r;
  const short* arow = srcp + rr * APS;

  const s16x8* wp = wt + (size_t)nt * 128 + lane;
  s16x8 wh = wp[0], wl = wp[64];
  #pragma unroll 1
  for (int kc = 0; kc < KC; ++kc) {
    s16x8 nh = (s16x8)0, nl = (s16x8)0;
    if (kc + 1 < KC) {
      const s16x8* np = wt + (size_t)((kc + 1) * NT32 + nt) * 128 + lane;
      nh = np[0]; nl = np[64];
    }
    const int ch = 2 * kc + h;
    s16x8 ah = (s16x8)0, al = (s16x8)0;
    if (ch < 25) { const short* p = arow + ch * 16; ah = *(const s16x8*)p; al = *(const s16x8*)(p + 8); }
    __builtin_amdgcn_s_setprio(1);
    acc = __builtin_amdgcn_mfma_f32_32x32x16_bf16(wh, ah, acc, 0, 0, 0);
    acc = __builtin_amdgcn_mfma_f32_32x32x16_bf16(wh, al, acc, 0, 0, 0);
    acc = __builtin_amdgcn_mfma_f32_32x32x16_bf16(wl, ah, acc, 0, 0, 0);
    __builtin_amdgcn_s_setprio(0);
    wh = nh; wl = nl;
  }

  if (r < LQ) {
    #pragma unroll
    for (int q2 = 0; q2 < 4; ++q2) {
      const int nb = nt * 32 + 8 * q2 + 4 * h;
      if (nb + 3 < DD) {
        float4 bv = *(const float4*)(bias + nb);
        float v0 = fmaxf(acc[q2*4+0] + bv.x, 0.f);
        float v1 = fmaxf(acc[q2*4+1] + bv.y, 0.f);
        float v2 = fmaxf(acc[q2*4+2] + bv.z, 0.f);
        float v3 = fmaxf(acc[q2*4+3] + bv.w, 0.f);
        uint2 ph;
        ph.x = (unsigned)bfbits(v0) | ((unsigned)bfbits(v1) << 16);
        ph.y = (unsigned)bfbits(v2) | ((unsigned)bfbits(v3) << 16);
        *(uint2*)(dstp + r * APS + (nb >> 3) * 16 + (nb & 7)) = ph;   // hi only
      }
    }
  }
}

// ---- 32x32 W2: C^T, HI-only src (2-term), f32 dst, no relu, prefetch ----
__device__ __forceinline__ void mm32_w2(
    const short* __restrict__ srcp, const s16x8* __restrict__ wt,
    const float* __restrict__ bias, float* __restrict__ dstf,
    int nt, int rt, int lane)
{
  const int h = lane >> 5, l31 = lane & 31;
  f32x16 acc = (f32x16)0.f;
  int r = rt * 32 + l31;
  int rr = (r >= LQ) ? 0 : r;
  const short* arow = srcp + rr * APS;

  const s16x8* wp = wt + (size_t)nt * 128 + lane;
  s16x8 wh = wp[0], wl = wp[64];
  #pragma unroll 1
  for (int kc = 0; kc < KC; ++kc) {
    s16x8 nh = (s16x8)0, nl = (s16x8)0;
    if (kc + 1 < KC) {
      const s16x8* np = wt + (size_t)((kc + 1) * NT32 + nt) * 128 + lane;
      nh = np[0]; nl = np[64];
    }
    const int ch = 2 * kc + h;
    s16x8 ah = (s16x8)0;
    if (ch < 25) ah = *(const s16x8*)(arow + ch * 16);   // hi only
    __builtin_amdgcn_s_setprio(1);
    acc = __builtin_amdgcn_mfma_f32_32x32x16_bf16(wh, ah, acc, 0, 0, 0);
    acc = __builtin_amdgcn_mfma_f32_32x32x16_bf16(wl, ah, acc, 0, 0, 0);
    __builtin_amdgcn_s_setprio(0);
    wh = nh; wl = nl;
  }

  if (r < LQ) {
    #pragma unroll
    for (int q2 = 0; q2 < 4; ++q2) {
      const int d0 = nt * 32 + 8 * q2 + 4 * h;
      if (d0 + 3 < DD) {
        float4 bv = *(const float4*)(bias + d0);
        float4 w4;
        w4.x = acc[q2*4+0] + bv.x; w4.y = acc[q2*4+1] + bv.y;
        w4.z = acc[q2*4+2] + bv.z; w4.w = acc[q2*4+3] + bv.w;
        *(float4*)(dstf + r * DD + d0) = w4;
      }
    }
  }
}

__global__ __launch_bounds__(NT)
void transformer_kernel(const int* __restrict__ tokens,
                        const float* __restrict__ emb,
                        const unsigned short* __restrict__ wbuf,
                        const float* __restrict__ bq, const float* __restrict__ bk,
                        const float* __restrict__ bv, const float* __restrict__ b1,
                        const float* __restrict__ b2,
                        const float* __restrict__ lng, const float* __restrict__ lnb,
                        float* __restrict__ out)
{
  __shared__ __align__(16) short xs_p[LQ * APS];
  __shared__ __align__(16) short q_p [LQ * APS];
  __shared__ __align__(16) short k_p [LQ * APS];
  __shared__ __align__(16) short vt_p[DD * VTS];
  __shared__ float rowsum[52];

  float* Sf  = (float*)q_p;          // S f32 [50][66]
  short* Pp  = q_p + 8192;           // P hi-only [50][PS]
  float* h2f = (float*)k_p;          // h2 f32 [50][200]

  const int b    = blockIdx.x;
  const int tid  = threadIdx.x;
  const int lane = tid & 63;
  const int wv   = tid >> 6;
  const int g    = lane >> 4, c = lane & 15;   // 16x16 frag coords

  // ---- embedding gather -> xs pair
  for (int o = tid; o < LQ * 25; o += NT) {
    int r = o / 25, ch = o % 25;
    int tok = tokens[b * LQ + r];
    const float* ep = emb + (size_t)tok * DD + ch * 8;
    float4 a0 = *(const float4*)ep;
    float4 a1 = *(const float4*)(ep + 4);
    float xv[8] = {a0.x, a0.y, a0.z, a0.w, a1.x, a1.y, a1.z, a1.w};
    s16x8 hh, ll;
    #pragma unroll
    for (int j = 0; j < 8; ++j) { short h, l; splitf(xv[j], h, l); hh[j] = h; ll[j] = l; }
    short* dp = xs_p + r * APS + ch * 16;
    *(s16x8*)dp = hh;
    *(s16x8*)(dp + 8) = ll;
  }
  __syncthreads();

  for (int layer = 0; layer < NBLK; ++layer) {
    const s16x8* wq  = (const s16x8*)wbuf + (size_t)(layer * 5 + 0) * MAT_U;
    const s16x8* wk  = (const s16x8*)wbuf + (size_t)(layer * 5 + 1) * MAT_U;
    const s16x8* wvv = (const s16x8*)wbuf + (size_t)(layer * 5 + 2) * MAT_U;
    const s16x8* w1  = (const s16x8*)wbuf + (size_t)(layer * 5 + 3) * MAT_U;
    const s16x8* w2  = (const s16x8*)wbuf + (size_t)(layer * 5 + 4) * MAT_U;
    const float* bql = bq + layer * DD;
    const float* bkl = bk + layer * DD;
    const float* bvl = bv + layer * DD;
    const float* b1l = b1 + layer * DD;
    const float* b2l = b2 + layer * DD;
    const float* gl  = lng + layer * DD;
    const float* bl  = lnb + layer * DD;

    if (layer == 0) {
      for (int r = wv; r < LQ; r += NW) {
        float s = 0.f;
        #pragma unroll
        for (int t = 0; t < 4; ++t) {
          int cc = lane + 64 * t;
          if (cc < DD) {
            const short* p = xs_p + r * APS + (cc >> 3) * 16 + (cc & 7);
            s += joinf(p[0], p[8]);
          }
        }
        s = wave_sum(s);
        if (lane == 0) rowsum[r] = s;
      }
    }

    // ---- phase 2: Q (waves 0-6) || K (waves 8-14)
    if (wv < 7)                   mm32_ct_pair(xs_p, wq, bql, q_p, wv, lane);
    else if (wv >= 8 && wv < 15)  mm32_ct_pair(xs_p, wk, bkl, k_p, wv - 8, lane);
    __syncthreads();

    // ---- phase 3: S = Q K^T (waves 8-15, 16x16)  ||  V projection (waves 0-6)
    f32x4 s0 = (f32x4)0.f, s1 = (f32x4)0.f;
    if (wv >= 8) {
      const int w8 = wv - 8;
      const int mt = w8 >> 1;
      const int nk0 = (w8 & 1) * 2;
      int qr = mt * 16 + c;          if (qr >= LQ) qr = 0;
      int kj0 = nk0 * 16 + c;        if (kj0 >= LQ) kj0 = 0;
      int kj1 = (nk0 + 1) * 16 + c;  if (kj1 >= LQ) kj1 = 0;
      const short* qrow = q_p + qr * APS;
      const short* k0r  = k_p + kj0 * APS;
      const short* k1r  = k_p + kj1 * APS;
      #pragma unroll 1
      for (int kt = 0; kt < 7; ++kt) {
        const int ch = kt * 4 + g;
        s16x8 qh = (s16x8)0, ql = (s16x8)0;
        s16x8 kh0 = (s16x8)0, kl0 = (s16x8)0, kh1 = (s16x8)0, kl1 = (s16x8)0;
        if (ch < 25) {
          qh  = *(const s16x8*)(qrow + ch * 16); ql  = *(const s16x8*)(qrow + ch * 16 + 8);
          kh0 = *(const s16x8*)(k0r + ch * 16);  kl0 = *(const s16x8*)(k0r + ch * 16 + 8);
          kh1 = *(const s16x8*)(k1r + ch * 16);  kl1 = *(const s16x8*)(k1r + ch * 16 + 8);
        }
        __builtin_amdgcn_s_setprio(1);
        s0 = __builtin_amdgcn_mfma_f32_16x16x32_bf16(qh, kh0, s0, 0, 0, 0);
        s0 = __builtin_amdgcn_mfma_f32_16x16x32_bf16(ql, kh0, s0, 0, 0, 0);
        s0 = __builtin_amdgcn_mfma_f32_16x16x32_bf16(qh, kl0, s0, 0, 0, 0);
        s1 = __builtin_amdgcn_mfma_f32_16x16x32_bf16(qh, kh1, s1, 0, 0, 0);
        s1 = __builtin_amdgcn_mfma_f32_16x16x32_bf16(ql, kh1, s1, 0, 0, 0);
        s1 = __builtin_amdgcn_mfma_f32_16x16x32_bf16(qh, kl1, s1, 0, 0, 0);
        __builtin_amdgcn_s_setprio(0);
      }
    } else if (wv < 7) {
      mm32_v(xs_p, wvv, bvl, vt_p, wv, lane);
    }
    __syncthreads();   // all q_p reads done -> S may overwrite

    // ---- phase 4: write S (scaled + key-masked) into Sf
    if (wv >= 8) {
      const int w8 = wv - 8;
      const int mt = w8 >> 1;
      const int nk0 = (w8 & 1) * 2;
      #pragma unroll
      for (int t = 0; t < 2; ++t) {
        const int j = (nk0 + t) * 16 + c;
        const f32x4 sa = t ? s1 : s0;
        const bool km = (j < LQ) && (rowsum[j] != 0.0f);
        #pragma unroll
        for (int q = 0; q < 4; ++q) {
          const int qi = mt * 16 + g * 4 + q;
          if (qi < LQ) Sf[qi * SS + j] = km ? sa[q] * SCALE : NEGC;
        }
      }
    }
    __syncthreads();

    // ---- phase 5: softmax rows -> P (hi only)
    for (int r = wv; r < LQ; r += NW) {
      float sm = -INFINITY;
      if (lane < LQ) sm = Sf[r * SS + lane];
      float m = wave_max(sm);
      float e = (lane < LQ) ? __expf(sm - m) : 0.0f;
      float ssum = wave_sum(e);
      float qm = (rowsum[r] == 0.0f) ? 0.0f : 1.0f;
      float a = e / ssum * qm;
      Pp[r * PS + (lane >> 3) * 16 + (lane & 7)] = (short)bfbits(a);
    }
    __syncthreads();

    // ---- phase 6: out^T = V^T @ P^T (P hi-only); residual RMW into xs pair
    if (wv < 13) {
      const int mt = wv;
      f32x4 pa[4];
      #pragma unroll
      for (int nq = 0; nq < 4; ++nq) pa[nq] = (f32x4)0.f;
      int vr = mt * 16 + c; if (vr >= DD) vr = 0;
      const short* vrow = vt_p + vr * VTS;
      #pragma unroll
      for (int kt = 0; kt < 2; ++kt) {
        s16x8 vh = *(const s16x8*)(vrow + (kt * 4 + g) * 8);
        __builtin_amdgcn_s_setprio(1);
        #pragma unroll
        for (int nq = 0; nq < 4; ++nq) {
          int pr = nq * 16 + c; if (pr >= LQ) pr = 0;
          s16x8 pbh = *(const s16x8*)(Pp + pr * PS + (kt * 4 + g) * 16);
          pa[nq] = __builtin_amdgcn_mfma_f32_16x16x32_bf16(vh, pbh, pa[nq], 0, 0, 0);
        }
        __builtin_amdgcn_s_setprio(0);
      }
      const int d0 = mt * 16 + g * 4;
      if (d0 + 3 < DD) {
        #pragma unroll
        for (int nq = 0; nq < 4; ++nq) {
          const int qq = nq * 16 + c;
          if (qq < LQ) {
            short* base = xs_p + qq * APS + (d0 >> 3) * 16 + (d0 & 7);
            uint2 ph = *(const uint2*)base;
            uint2 pl = *(const uint2*)(base + 8);
            float f0 = joinf((short)(ph.x & 0xFFFF), (short)(pl.x & 0xFFFF)) + pa[nq][0];
            float f1 = joinf((short)(ph.x >> 16),    (short)(pl.x >> 16))    + pa[nq][1];
            float f2 = joinf((short)(ph.y & 0xFFFF), (short)(pl.y & 0xFFFF)) + pa[nq][2];
            float f3 = joinf((short)(ph.y >> 16),    (short)(pl.y >> 16))    + pa[nq][3];
            short h0,l0,h1,l1,h2,l2,h3,l3;
            splitf(f0,h0,l0); splitf(f1,h1,l1); splitf(f2,h2,l2); splitf(f3,h3,l3);
            ph.x = (unsigned short)h0 | ((unsigned)(unsigned short)h1 << 16);
            ph.y = (unsigned short)h2 | ((unsigned)(unsigned short)h3 << 16);
            pl.x = (unsigned short)l0 | ((unsigned)(unsigned short)l1 << 16);
            pl.y = (unsigned short)l2 | ((unsigned)(unsigned short)l3 << 16);
            *(uint2*)base = ph;
            *(uint2*)(base + 8) = pl;
          }
        }
      }
    }
    __syncthreads();

    // ---- phase 7: W1 -> h1 (hi-only) in q_p  (14 waves)
    if (wv < 14) mm32_w1(xs_p, w1, b1l, q_p, wv >> 1, wv & 1, lane);
    __syncthreads();
    // ---- phase 8: W2 -> h2 f32 in k_p  (14 waves, h1 hi-only src)
    if (wv < 14) mm32_w2(q_p, w2, b2l, h2f, wv >> 1, wv & 1, lane);
    __syncthreads();

    // ---- phase 9: LayerNorm + residual -> xs pair; next-layer rowsum
    for (int r = wv; r < LQ; r += NW) {
      float hv[4];
      #pragma unroll
      for (int t = 0; t < 4; ++t) {
        int cc = lane + 64 * t;
        hv[t] = (cc < DD) ? h2f[r * DD + cc] : 0.f;
      }
      float mu = wave_sum(hv[0] + hv[1] + hv[2] + hv[3]) * (1.0f / 200.0f);
      float d0 = hv[0] - mu, d1 = hv[1] - mu, d2 = hv[2] - mu;
      float d3 = (lane + 192 < DD) ? (hv[3] - mu) : 0.f;
      float var = wave_sum(d0 * d0 + d1 * d1 + d2 * d2 + d3 * d3) * (1.0f / 200.0f);
      float inv = 1.0f / sqrtf(var + 1e-8f);
      float dd4[4] = {d0, d1, d2, d3};
      float rs = 0.f;
      #pragma unroll
      for (int t = 0; t < 4; ++t) {
        int cc = lane + 64 * t;
        if (cc < DD) {
          short* hp = xs_p + r * APS + (cc >> 3) * 16 + (cc & 7);
          float nv = dd4[t] * inv * gl[cc] + bl[cc] + joinf(hp[0], hp[8]);
          rs += nv;
          short h, l; splitf(nv, h, l);
          hp[0] = h; hp[8] = l;
        }
      }
      rs = wave_sum(rs);
      if (lane == 0) rowsum[r] = rs;
    }
    __syncthreads();
  }

  // ---- write result
  for (int o = tid; o < LQ * 25; o += NT) {
    int r = o / 25, ch = o % 25;
    const short* sp = xs_p + r * APS + ch * 16;
    s16x8 hh = *(const s16x8*)sp;
    s16x8 ll = *(const s16x8*)(sp + 8);
    float4 o0, o1;
    o0.x = joinf(hh[0], ll[0]); o0.y = joinf(hh[1], ll[1]);
    o0.z = joinf(hh[2], ll[2]); o0.w = joinf(hh[3], ll[3]);
    o1.x = joinf(hh[4], ll[4]); o1.y = joinf(hh[5], ll[5]);
    o1.z = joinf(hh[6], ll[6]); o1.w = joinf(hh[7], ll[7]);
    float* op = out + ((size_t)b * LQ + r) * DD + ch * 8;
    *(float4*)op = o0;
    *(float4*)(op + 4) = o1;
  }
}

extern "C" void kernel_launch(void* const* d_in, const int* in_sizes, int n_in,
                              void* d_out, int out_size, void* d_ws, size_t ws_size,
                              hipStream_t stream) {
  const int*   tokens = (const int*)  d_in[0];
  const float* emb    = (const float*)d_in[1];
  const float* Wq     = (const float*)d_in[2];
  const float* bq     = (const float*)d_in[3];
  const float* Wk     = (const float*)d_in[4];
  const float* bk     = (const float*)d_in[5];
  const float* Wv     = (const float*)d_in[6];
  const float* bv     = (const float*)d_in[7];
  const float* W1     = (const float*)d_in[8];
  const float* b1     = (const float*)d_in[9];
  const float* W2     = (const float*)d_in[10];
  const float* b2     = (const float*)d_in[11];
  const float* lng    = (const float*)d_in[12];
  const float* lnb    = (const float*)d_in[13];
  float* out = (float*)d_out;
  unsigned short* wbuf = (unsigned short*)d_ws;

  hipLaunchKernelGGL(swizzle_w, dim3(15 * KC * NT32), dim3(64), 0, stream,
                     Wq, Wk, Wv, W1, W2, wbuf);

  const int B = in_sizes[0] / LQ;   // 4096
  hipLaunchKernelGGL(transformer_kernel, dim3(B), dim3(NT), 0, stream,
                     tokens, emb, wbuf, bq, bk, bv, b1, b2, lng, lnb, out);
}

// Round 19
// 1662.292 us; speedup vs baseline: 1.1569x; 1.0573x over previous
//
#include <hip/hip_runtime.h>
#include <hip/hip_bf16.h>
#include <math.h>

#define LQ 50
#define DD 200
#define NBLK 3
#define NT 1024
#define NW 16

#define KC 13          // k-chunks of 16 for 32x32 MFMA (208 >= 200)
#define NT32 7         // n-tiles of 32 (224 >= 200)
#define MAT_U (KC * NT32 * 128)  // s16x8 units per matrix

#define APS 408   // pair-buffer row stride (shorts)
#define VTS 72    // v_T row stride (shorts)
#define PS  136   // P row stride (shorts)
#define SS  66    // S row stride (floats)

#define NEGC (-4294967295.0f)
#define SCALE 0.07071067811865475f

typedef __attribute__((ext_vector_type(4)))  float f32x4;
typedef __attribute__((ext_vector_type(16))) float f32x16;
typedef __attribute__((ext_vector_type(8)))  short s16x8;

__device__ __forceinline__ unsigned short bf16_rne(float x) {
  unsigned u = __float_as_uint(x);
  unsigned r = u + 0x7FFF + ((u >> 16) & 1);
  return (unsigned short)(r >> 16);
}
__device__ __forceinline__ float bf16_f(unsigned short h) {
  return __uint_as_float((unsigned)h << 16);
}
__device__ __forceinline__ void splitf(float x, short& h, short& l) {
  __hip_bfloat16 bh = __float2bfloat16(x);
  float hf = __bfloat162float(bh);
  __hip_bfloat16 bl = __float2bfloat16(x - hf);
  h = (short)__builtin_bit_cast(unsigned short, bh);
  l = (short)__builtin_bit_cast(unsigned short, bl);
}
__device__ __forceinline__ unsigned short bfbits(float x) {
  __hip_bfloat16 bh = __float2bfloat16(x);
  return __builtin_bit_cast(unsigned short, bh);
}
__device__ __forceinline__ float joinf(short h, short l) {
  return __bfloat162float(__builtin_bit_cast(__hip_bfloat16, (unsigned short)h)) +
         __bfloat162float(__builtin_bit_cast(__hip_bfloat16, (unsigned short)l));
}

__device__ __forceinline__ float wave_sum(float v) {
  #pragma unroll
  for (int off = 32; off > 0; off >>= 1) v += __shfl_xor(v, off, 64);
  return v;
}
__device__ __forceinline__ float wave_max(float v) {
  #pragma unroll
  for (int off = 32; off > 0; off >>= 1) v = fmaxf(v, __shfl_xor(v, off, 64));
  return v;
}

// ---- pre-swizzle: W f32 [DD][DD] -> bf16 hi/lo fragments for 32x32x16 ----
// chunk (mat, kc, nt): lane l covers n = nt*32+(l&31), k = kc*16+(l>>5)*8+j
__global__ __launch_bounds__(64)
void swizzle_w(const float* __restrict__ Wq, const float* __restrict__ Wk,
               const float* __restrict__ Wv, const float* __restrict__ W1,
               const float* __restrict__ W2, unsigned short* __restrict__ wbuf)
{
  int t = blockIdx.x;             // 15*KC*NT32
  int nt = t % NT32; t /= NT32;
  int kc = t % KC;  t /= KC;
  int mat = t;
  int layer = mat / 5, which = mat % 5;
  const float* W;
  switch (which) {
    case 0: W = Wq; break;
    case 1: W = Wk; break;
    case 2: W = Wv; break;
    case 3: W = W1; break;
    default: W = W2; break;
  }
  W += (size_t)layer * DD * DD;

  const int l = threadIdx.x;
  const int n = nt * 32 + (l & 31);
  const int kb = kc * 16 + (l >> 5) * 8;
  s16x8 vh, vl;
  #pragma unroll
  for (int j = 0; j < 8; ++j) {
    int k = kb + j;
    float w = (k < DD && n < DD) ? W[k * DD + n] : 0.0f;
    unsigned short h = bf16_rne(w);
    unsigned short lo = bf16_rne(w - bf16_f(h));
    vh[j] = (short)h;
    vl[j] = (short)lo;
  }
  size_t base = ((size_t)((mat * KC + kc) * NT32 + nt)) * 1024 + l * 8;
  *(s16x8*)(wbuf + base)       = vh;
  *(s16x8*)(wbuf + base + 512) = vl;
}

// ---- 32x32 matmul, C^T (A=W, B=x pair), pair dst with relu. nt in 0..6 ----
__device__ __forceinline__ void mm32_ct_pair(
    const short* __restrict__ srcp, const s16x8* __restrict__ wt,
    const float* __restrict__ bias, short* __restrict__ dstp, int nt, int lane)
{
  const int h = lane >> 5, l31 = lane & 31;
  f32x16 acc0 = (f32x16)0.f, acc1 = (f32x16)0.f;
  int r1 = 32 + l31; if (r1 >= LQ) r1 = 0;
  const short* arow0 = srcp + l31 * APS;       // rows 0..31 all valid
  const short* arow1 = srcp + r1 * APS;

  #pragma unroll 1
  for (int kc = 0; kc < KC; ++kc) {
    const s16x8* wp = wt + (size_t)(kc * NT32 + nt) * 128 + lane;
    s16x8 wh = wp[0], wl = wp[64];
    const int ch = 2 * kc + h;
    const bool ok = (ch < 25);
    {
      s16x8 ah = (s16x8)0, al = (s16x8)0;
      if (ok) { const short* p = arow0 + ch * 16; ah = *(const s16x8*)p; al = *(const s16x8*)(p + 8); }
      acc0 = __builtin_amdgcn_mfma_f32_32x32x16_bf16(wh, ah, acc0, 0, 0, 0);
      acc0 = __builtin_amdgcn_mfma_f32_32x32x16_bf16(wh, al, acc0, 0, 0, 0);
      acc0 = __builtin_amdgcn_mfma_f32_32x32x16_bf16(wl, ah, acc0, 0, 0, 0);
    }
    {
      s16x8 ah = (s16x8)0, al = (s16x8)0;
      if (ok) { const short* p = arow1 + ch * 16; ah = *(const s16x8*)p; al = *(const s16x8*)(p + 8); }
      acc1 = __builtin_amdgcn_mfma_f32_32x32x16_bf16(wh, ah, acc1, 0, 0, 0);
      acc1 = __builtin_amdgcn_mfma_f32_32x32x16_bf16(wh, al, acc1, 0, 0, 0);
      acc1 = __builtin_amdgcn_mfma_f32_32x32x16_bf16(wl, ah, acc1, 0, 0, 0);
    }
  }

  // C^T: lane holds n_local = (reg&3)+8*(reg>>2)+4h for r = rt*32 + l31
  #pragma unroll
  for (int rt = 0; rt < 2; ++rt) {
    const int r = rt * 32 + l31;
    if (r < LQ) {
      #pragma unroll
      for (int q2 = 0; q2 < 4; ++q2) {
        const int nb = nt * 32 + 8 * q2 + 4 * h;
        if (nb + 3 < DD) {
          float4 bv = *(const float4*)(bias + nb);
          float v0 = fmaxf((rt ? acc1[q2*4+0] : acc0[q2*4+0]) + bv.x, 0.f);
          float v1 = fmaxf((rt ? acc1[q2*4+1] : acc0[q2*4+1]) + bv.y, 0.f);
          float v2 = fmaxf((rt ? acc1[q2*4+2] : acc0[q2*4+2]) + bv.z, 0.f);
          float v3 = fmaxf((rt ? acc1[q2*4+3] : acc0[q2*4+3]) + bv.w, 0.f);
          short h0,l0,h1,l1,h2,l2,h3,l3;
          splitf(v0,h0,l0); splitf(v1,h1,l1); splitf(v2,h2,l2); splitf(v3,h3,l3);
          uint2 ph, pl;
          ph.x = (unsigned short)h0 | ((unsigned)(unsigned short)h1 << 16);
          ph.y = (unsigned short)h2 | ((unsigned)(unsigned short)h3 << 16);
          pl.x = (unsigned short)l0 | ((unsigned)(unsigned short)l1 << 16);
          pl.y = (unsigned short)l2 | ((unsigned)(unsigned short)l3 << 16);
          short* base = dstp + r * APS + (nb >> 3) * 16 + (nb & 7);
          *(uint2*)base = ph;
          *(uint2*)(base + 8) = pl;
        }
      }
    }
  }
}

// ---- 32x32 V projection (A=x pair, B=W), hi-only transposed dst ----
__device__ __forceinline__ void mm32_v(
    const short* __restrict__ srcp, const s16x8* __restrict__ wt,
    const float* __restrict__ bias, short* __restrict__ vtp, int nt, int lane)
{
  const int h = lane >> 5, l31 = lane & 31;
  f32x16 acc0 = (f32x16)0.f, acc1 = (f32x16)0.f;
  int r1 = 32 + l31; if (r1 >= LQ) r1 = 0;
  const short* arow0 = srcp + l31 * APS;
  const short* arow1 = srcp + r1 * APS;

  #pragma unroll 1
  for (int kc = 0; kc < KC; ++kc) {
    const s16x8* wp = wt + (size_t)(kc * NT32 + nt) * 128 + lane;
    s16x8 wh = wp[0], wl = wp[64];
    const int ch = 2 * kc + h;
    const bool ok = (ch < 25);
    {
      s16x8 ah = (s16x8)0, al = (s16x8)0;
      if (ok) { const short* p = arow0 + ch * 16; ah = *(const s16x8*)p; al = *(const s16x8*)(p + 8); }
      acc0 = __builtin_amdgcn_mfma_f32_32x32x16_bf16(ah, wh, acc0, 0, 0, 0);
      acc0 = __builtin_amdgcn_mfma_f32_32x32x16_bf16(al, wh, acc0, 0, 0, 0);
      acc0 = __builtin_amdgcn_mfma_f32_32x32x16_bf16(ah, wl, acc0, 0, 0, 0);
    }
    {
      s16x8 ah = (s16x8)0, al = (s16x8)0;
      if (ok) { const short* p = arow1 + ch * 16; ah = *(const s16x8*)p; al = *(const s16x8*)(p + 8); }
      acc1 = __builtin_amdgcn_mfma_f32_32x32x16_bf16(ah, wh, acc1, 0, 0, 0);
      acc1 = __builtin_amdgcn_mfma_f32_32x32x16_bf16(al, wh, acc1, 0, 0, 0);
      acc1 = __builtin_amdgcn_mfma_f32_32x32x16_bf16(ah, wl, acc1, 0, 0, 0);
    }
  }

  // C: lane holds d = nt*32 + l31 (col), r_local = (reg&3)+8*(reg>>2)+4h + 32*mt
  const int d = nt * 32 + l31;
  if (d < DD) {
    const float bvs = bias[d];
    #pragma unroll
    for (int mt2 = 0; mt2 < 2; ++mt2) {
      #pragma unroll
      for (int q2 = 0; q2 < 4; ++q2) {
        const int rb = mt2 * 32 + 8 * q2 + 4 * h;
        float vv[4];
        #pragma unroll
        for (int e = 0; e < 4; ++e) {
          const int r = rb + e;
          float v = (mt2 ? acc1[q2*4+e] : acc0[q2*4+e]) + bvs;
          vv[e] = (r < LQ) ? fmaxf(v, 0.f) : 0.f;
        }
        uint2 pk;
        pk.x = (unsigned)bfbits(vv[0]) | ((unsigned)bfbits(vv[1]) << 16);
        pk.y = (unsigned)bfbits(vv[2]) | ((unsigned)bfbits(vv[3]) << 16);
        *(uint2*)(vtp + d * VTS + (rb >> 3) * 8 + (rb & 7)) = pk;
      }
    }
  }
}

// ---- 32x32 W1: C^T, pair-src (3-term), HI-ONLY pair dst, relu, prefetch ----
__device__ __forceinline__ void mm32_w1(
    const short* __restrict__ srcp, const s16x8* __restrict__ wt,
    const float* __restrict__ bias, short* __restrict__ dstp,
    int nt, int rt, int lane)
{
  const int h = lane >> 5, l31 = lane & 31;
  f32x16 acc = (f32x16)0.f;
  int r = rt * 32 + l31;
  int rr = (r >= LQ) ? 0 : r;
  const short* arow = srcp + rr * APS;

  const s16x8* wp = wt + (size_t)nt * 128 + lane;
  s16x8 wh = wp[0], wl = wp[64];
  #pragma unroll 1
  for (int kc = 0; kc < KC; ++kc) {
    s16x8 nh = (s16x8)0, nl = (s16x8)0;
    if (kc + 1 < KC) {
      const s16x8* np = wt + (size_t)((kc + 1) * NT32 + nt) * 128 + lane;
      nh = np[0]; nl = np[64];
    }
    const int ch = 2 * kc + h;
    s16x8 ah = (s16x8)0, al = (s16x8)0;
    if (ch < 25) { const short* p = arow + ch * 16; ah = *(const s16x8*)p; al = *(const s16x8*)(p + 8); }
    acc = __builtin_amdgcn_mfma_f32_32x32x16_bf16(wh, ah, acc, 0, 0, 0);
    acc = __builtin_amdgcn_mfma_f32_32x32x16_bf16(wh, al, acc, 0, 0, 0);
    acc = __builtin_amdgcn_mfma_f32_32x32x16_bf16(wl, ah, acc, 0, 0, 0);
    wh = nh; wl = nl;
  }

  if (r < LQ) {
    #pragma unroll
    for (int q2 = 0; q2 < 4; ++q2) {
      const int nb = nt * 32 + 8 * q2 + 4 * h;
      if (nb + 3 < DD) {
        float4 bv = *(const float4*)(bias + nb);
        float v0 = fmaxf(acc[q2*4+0] + bv.x, 0.f);
        float v1 = fmaxf(acc[q2*4+1] + bv.y, 0.f);
        float v2 = fmaxf(acc[q2*4+2] + bv.z, 0.f);
        float v3 = fmaxf(acc[q2*4+3] + bv.w, 0.f);
        uint2 ph;
        ph.x = (unsigned)bfbits(v0) | ((unsigned)bfbits(v1) << 16);
        ph.y = (unsigned)bfbits(v2) | ((unsigned)bfbits(v3) << 16);
        *(uint2*)(dstp + r * APS + (nb >> 3) * 16 + (nb & 7)) = ph;   // hi only
      }
    }
  }
}

// ---- 32x32 W2: C^T, HI-only src (2-term), f32 dst, no relu, prefetch ----
__device__ __forceinline__ void mm32_w2(
    const short* __restrict__ srcp, const s16x8* __restrict__ wt,
    const float* __restrict__ bias, float* __restrict__ dstf,
    int nt, int rt, int lane)
{
  const int h = lane >> 5, l31 = lane & 31;
  f32x16 acc = (f32x16)0.f;
  int r = rt * 32 + l31;
  int rr = (r >= LQ) ? 0 : r;
  const short* arow = srcp + rr * APS;

  const s16x8* wp = wt + (size_t)nt * 128 + lane;
  s16x8 wh = wp[0], wl = wp[64];
  #pragma unroll 1
  for (int kc = 0; kc < KC; ++kc) {
    s16x8 nh = (s16x8)0, nl = (s16x8)0;
    if (kc + 1 < KC) {
      const s16x8* np = wt + (size_t)((kc + 1) * NT32 + nt) * 128 + lane;
      nh = np[0]; nl = np[64];
    }
    const int ch = 2 * kc + h;
    s16x8 ah = (s16x8)0;
    if (ch < 25) ah = *(const s16x8*)(arow + ch * 16);   // hi only
    acc = __builtin_amdgcn_mfma_f32_32x32x16_bf16(wh, ah, acc, 0, 0, 0);
    acc = __builtin_amdgcn_mfma_f32_32x32x16_bf16(wl, ah, acc, 0, 0, 0);
    wh = nh; wl = nl;
  }

  if (r < LQ) {
    #pragma unroll
    for (int q2 = 0; q2 < 4; ++q2) {
      const int d0 = nt * 32 + 8 * q2 + 4 * h;
      if (d0 + 3 < DD) {
        float4 bv = *(const float4*)(bias + d0);
        float4 w4;
        w4.x = acc[q2*4+0] + bv.x; w4.y = acc[q2*4+1] + bv.y;
        w4.z = acc[q2*4+2] + bv.z; w4.w = acc[q2*4+3] + bv.w;
        *(float4*)(dstf + r * DD + d0) = w4;
      }
    }
  }
}

__global__ __launch_bounds__(NT)
void transformer_kernel(const int* __restrict__ tokens,
                        const float* __restrict__ emb,
                        const unsigned short* __restrict__ wbuf,
                        const float* __restrict__ bq, const float* __restrict__ bk,
                        const float* __restrict__ bv, const float* __restrict__ b1,
                        const float* __restrict__ b2,
                        const float* __restrict__ lng, const float* __restrict__ lnb,
                        float* __restrict__ out)
{
  __shared__ __align__(16) short xs_p[LQ * APS];
  __shared__ __align__(16) short q_p [LQ * APS];
  __shared__ __align__(16) short k_p [LQ * APS];
  __shared__ __align__(16) short vt_p[DD * VTS];
  __shared__ float rowsum[52];

  float* Sf  = (float*)q_p;          // S f32 [50][66]
  short* Pp  = q_p + 8192;           // P hi-only [50][PS]
  float* h2f = (float*)k_p;          // h2 f32 [50][200]

  const int b    = blockIdx.x;
  const int tid  = threadIdx.x;
  const int lane = tid & 63;
  const int wv   = tid >> 6;
  const int g    = lane >> 4, c = lane & 15;   // 16x16 frag coords (phases 3-6)

  // ---- embedding gather -> xs pair
  for (int o = tid; o < LQ * 25; o += NT) {
    int r = o / 25, ch = o % 25;
    int tok = tokens[b * LQ + r];
    const float* ep = emb + (size_t)tok * DD + ch * 8;
    float4 a0 = *(const float4*)ep;
    float4 a1 = *(const float4*)(ep + 4);
    float xv[8] = {a0.x, a0.y, a0.z, a0.w, a1.x, a1.y, a1.z, a1.w};
    s16x8 hh, ll;
    #pragma unroll
    for (int j = 0; j < 8; ++j) { short h, l; splitf(xv[j], h, l); hh[j] = h; ll[j] = l; }
    short* dp = xs_p + r * APS + ch * 16;
    *(s16x8*)dp = hh;
    *(s16x8*)(dp + 8) = ll;
  }
  __syncthreads();

  for (int layer = 0; layer < NBLK; ++layer) {
    const s16x8* wq  = (const s16x8*)wbuf + (size_t)(layer * 5 + 0) * MAT_U;
    const s16x8* wk  = (const s16x8*)wbuf + (size_t)(layer * 5 + 1) * MAT_U;
    const s16x8* wvv = (const s16x8*)wbuf + (size_t)(layer * 5 + 2) * MAT_U;
    const s16x8* w1  = (const s16x8*)wbuf + (size_t)(layer * 5 + 3) * MAT_U;
    const s16x8* w2  = (const s16x8*)wbuf + (size_t)(layer * 5 + 4) * MAT_U;
    const float* bql = bq + layer * DD;
    const float* bkl = bk + layer * DD;
    const float* bvl = bv + layer * DD;
    const float* b1l = b1 + layer * DD;
    const float* b2l = b2 + layer * DD;
    const float* gl  = lng + layer * DD;
    const float* bl  = lnb + layer * DD;

    if (layer == 0) {
      for (int r = wv; r < LQ; r += NW) {
        float s = 0.f;
        #pragma unroll
        for (int t = 0; t < 4; ++t) {
          int cc = lane + 64 * t;
          if (cc < DD) {
            const short* p = xs_p + r * APS + (cc >> 3) * 16 + (cc & 7);
            s += joinf(p[0], p[8]);
          }
        }
        s = wave_sum(s);
        if (lane == 0) rowsum[r] = s;
      }
    }

    // ---- phase 2: Q (waves 0-6) || K (waves 8-14)
    if (wv < 7)                   mm32_ct_pair(xs_p, wq, bql, q_p, wv, lane);
    else if (wv >= 8 && wv < 15)  mm32_ct_pair(xs_p, wk, bkl, k_p, wv - 8, lane);
    __syncthreads();

    // ---- phase 3: S = Q K^T (waves 8-15, 16x16)  ||  V projection (waves 0-6)
    f32x4 s0 = (f32x4)0.f, s1 = (f32x4)0.f;
    if (wv >= 8) {
      const int w8 = wv - 8;
      const int mt = w8 >> 1;
      const int nk0 = (w8 & 1) * 2;
      int qr = mt * 16 + c;          if (qr >= LQ) qr = 0;
      int kj0 = nk0 * 16 + c;        if (kj0 >= LQ) kj0 = 0;
      int kj1 = (nk0 + 1) * 16 + c;  if (kj1 >= LQ) kj1 = 0;
      const short* qrow = q_p + qr * APS;
      const short* k0r  = k_p + kj0 * APS;
      const short* k1r  = k_p + kj1 * APS;
      #pragma unroll 1
      for (int kt = 0; kt < 7; ++kt) {
        const int ch = kt * 4 + g;
        s16x8 qh = (s16x8)0, ql = (s16x8)0;
        s16x8 kh0 = (s16x8)0, kl0 = (s16x8)0, kh1 = (s16x8)0, kl1 = (s16x8)0;
        if (ch < 25) {
          qh  = *(const s16x8*)(qrow + ch * 16); ql  = *(const s16x8*)(qrow + ch * 16 + 8);
          kh0 = *(const s16x8*)(k0r + ch * 16);  kl0 = *(const s16x8*)(k0r + ch * 16 + 8);
          kh1 = *(const s16x8*)(k1r + ch * 16);  kl1 = *(const s16x8*)(k1r + ch * 16 + 8);
        }
        s0 = __builtin_amdgcn_mfma_f32_16x16x32_bf16(qh, kh0, s0, 0, 0, 0);
        s0 = __builtin_amdgcn_mfma_f32_16x16x32_bf16(ql, kh0, s0, 0, 0, 0);
        s0 = __builtin_amdgcn_mfma_f32_16x16x32_bf16(qh, kl0, s0, 0, 0, 0);
        s1 = __builtin_amdgcn_mfma_f32_16x16x32_bf16(qh, kh1, s1, 0, 0, 0);
        s1 = __builtin_amdgcn_mfma_f32_16x16x32_bf16(ql, kh1, s1, 0, 0, 0);
        s1 = __builtin_amdgcn_mfma_f32_16x16x32_bf16(qh, kl1, s1, 0, 0, 0);
      }
    } else if (wv < 7) {
      mm32_v(xs_p, wvv, bvl, vt_p, wv, lane);
    }
    __syncthreads();   // all q_p reads done -> S may overwrite

    // ---- phase 4: write S (scaled + key-masked) into Sf
    if (wv >= 8) {
      const int w8 = wv - 8;
      const int mt = w8 >> 1;
      const int nk0 = (w8 & 1) * 2;
      #pragma unroll
      for (int t = 0; t < 2; ++t) {
        const int j = (nk0 + t) * 16 + c;
        const f32x4 sa = t ? s1 : s0;
        const bool km = (j < LQ) && (rowsum[j] != 0.0f);
        #pragma unroll
        for (int q = 0; q < 4; ++q) {
          const int qi = mt * 16 + g * 4 + q;
          if (qi < LQ) Sf[qi * SS + j] = km ? sa[q] * SCALE : NEGC;
        }
      }
    }
    __syncthreads();

    // ---- phase 5: softmax rows -> P (hi only)
    for (int r = wv; r < LQ; r += NW) {
      float sm = -INFINITY;
      if (lane < LQ) sm = Sf[r * SS + lane];
      float m = wave_max(sm);
      float e = (lane < LQ) ? __expf(sm - m) : 0.0f;
      float ssum = wave_sum(e);
      float qm = (rowsum[r] == 0.0f) ? 0.0f : 1.0f;
      float a = e / ssum * qm;
      Pp[r * PS + (lane >> 3) * 16 + (lane & 7)] = (short)bfbits(a);
    }
    __syncthreads();

    // ---- phase 6: out^T = V^T @ P^T (P hi-only); residual RMW into xs pair
    if (wv < 13) {
      const int mt = wv;
      f32x4 pa[4];
      #pragma unroll
      for (int nq = 0; nq < 4; ++nq) pa[nq] = (f32x4)0.f;
      int vr = mt * 16 + c; if (vr >= DD) vr = 0;
      const short* vrow = vt_p + vr * VTS;
      #pragma unroll
      for (int kt = 0; kt < 2; ++kt) {
        s16x8 vh = *(const s16x8*)(vrow + (kt * 4 + g) * 8);
        #pragma unroll
        for (int nq = 0; nq < 4; ++nq) {
          int pr = nq * 16 + c; if (pr >= LQ) pr = 0;
          s16x8 pbh = *(const s16x8*)(Pp + pr * PS + (kt * 4 + g) * 16);
          pa[nq] = __builtin_amdgcn_mfma_f32_16x16x32_bf16(vh, pbh, pa[nq], 0, 0, 0);
        }
      }
      const int d0 = mt * 16 + g * 4;
      if (d0 + 3 < DD) {
        #pragma unroll
        for (int nq = 0; nq < 4; ++nq) {
          const int qq = nq * 16 + c;
          if (qq < LQ) {
            short* base = xs_p + qq * APS + (d0 >> 3) * 16 + (d0 & 7);
            uint2 ph = *(const uint2*)base;
            uint2 pl = *(const uint2*)(base + 8);
            float f0 = joinf((short)(ph.x & 0xFFFF), (short)(pl.x & 0xFFFF)) + pa[nq][0];
            float f1 = joinf((short)(ph.x >> 16),    (short)(pl.x >> 16))    + pa[nq][1];
            float f2 = joinf((short)(ph.y & 0xFFFF), (short)(pl.y & 0xFFFF)) + pa[nq][2];
            float f3 = joinf((short)(ph.y >> 16),    (short)(pl.y >> 16))    + pa[nq][3];
            short h0,l0,h1,l1,h2,l2,h3,l3;
            splitf(f0,h0,l0); splitf(f1,h1,l1); splitf(f2,h2,l2); splitf(f3,h3,l3);
            ph.x = (unsigned short)h0 | ((unsigned)(unsigned short)h1 << 16);
            ph.y = (unsigned short)h2 | ((unsigned)(unsigned short)h3 << 16);
            pl.x = (unsigned short)l0 | ((unsigned)(unsigned short)l1 << 16);
            pl.y = (unsigned short)l2 | ((unsigned)(unsigned short)l3 << 16);
            *(uint2*)base = ph;
            *(uint2*)(base + 8) = pl;
          }
        }
      }
    }
    __syncthreads();

    // ---- phase 7: W1 -> h1 (hi-only) in q_p  (14 waves)
    if (wv < 14) mm32_w1(xs_p, w1, b1l, q_p, wv >> 1, wv & 1, lane);
    __syncthreads();
    // ---- phase 8: W2 -> h2 f32 in k_p  (14 waves, h1 hi-only src)
    if (wv < 14) mm32_w2(q_p, w2, b2l, h2f, wv >> 1, wv & 1, lane);
    __syncthreads();

    // ---- phase 9: LayerNorm + residual -> xs pair; next-layer rowsum
    for (int r = wv; r < LQ; r += NW) {
      float hv[4];
      #pragma unroll
      for (int t = 0; t < 4; ++t) {
        int cc = lane + 64 * t;
        hv[t] = (cc < DD) ? h2f[r * DD + cc] : 0.f;
      }
      float mu = wave_sum(hv[0] + hv[1] + hv[2] + hv[3]) * (1.0f / 200.0f);
      float d0 = hv[0] - mu, d1 = hv[1] - mu, d2 = hv[2] - mu;
      float d3 = (lane + 192 < DD) ? (hv[3] - mu) : 0.f;
      float var = wave_sum(d0 * d0 + d1 * d1 + d2 * d2 + d3 * d3) * (1.0f / 200.0f);
      float inv = 1.0f / sqrtf(var + 1e-8f);
      float dd4[4] = {d0, d1, d2, d3};
      float rs = 0.f;
      #pragma unroll
      for (int t = 0; t < 4; ++t) {
        int cc = lane + 64 * t;
        if (cc < DD) {
          short* hp = xs_p + r * APS + (cc >> 3) * 16 + (cc & 7);
          float nv = dd4[t] * inv * gl[cc] + bl[cc] + joinf(hp[0], hp[8]);
          rs += nv;
          short h, l; splitf(nv, h, l);
          hp[0] = h; hp[8] = l;
        }
      }
      rs = wave_sum(rs);
      if (lane == 0) rowsum[r] = rs;
    }
    __syncthreads();
  }

  // ---- write result
  for (int o = tid; o < LQ * 25; o += NT) {
    int r = o / 25, ch = o % 25;
    const short* sp = xs_p + r * APS + ch * 16;
    s16x8 hh = *(const s16x8*)sp;
    s16x8 ll = *(const s16x8*)(sp + 8);
    float4 o0, o1;
    o0.x = joinf(hh[0], ll[0]); o0.y = joinf(hh[1], ll[1]);
    o0.z = joinf(hh[2], ll[2]); o0.w = joinf(hh[3], ll[3]);
    o1.x = joinf(hh[4], ll[4]); o1.y = joinf(hh[5], ll[5]);
    o1.z = joinf(hh[6], ll[6]); o1.w = joinf(hh[7], ll[7]);
    float* op = out + ((size_t)b * LQ + r) * DD + ch * 8;
    *(float4*)op = o0;
    *(float4*)(op + 4) = o1;
  }
}

extern "C" void kernel_launch(void* const* d_in, const int* in_sizes, int n_in,
                              void* d_out, int out_size, void* d_ws, size_t ws_size,
                              hipStream_t stream) {
  const int*   tokens = (const int*)  d_in[0];
  const float* emb    = (const float*)d_in[1];
  const float* Wq     = (const float*)d_in[2];
  const float* bq     = (const float*)d_in[3];
  const float* Wk     = (const float*)d_in[4];
  const float* bk     = (const float*)d_in[5];
  const float* Wv     = (const float*)d_in[6];
  const float* bv     = (const float*)d_in[7];
  const float* W1     = (const float*)d_in[8];
  const float* b1     = (const float*)d_in[9];
  const float* W2     = (const float*)d_in[10];
  const float* b2     = (const float*)d_in[11];
  const float* lng    = (const float*)d_in[12];
  const float* lnb    = (const float*)d_in[13];
  float* out = (float*)d_out;
  unsigned short* wbuf = (unsigned short*)d_ws;

  hipLaunchKernelGGL(swizzle_w, dim3(15 * KC * NT32), dim3(64), 0, stream,
                     Wq, Wk, Wv, W1, W2, wbuf);

  const int B = in_sizes[0] / LQ;   // 4096
  hipLaunchKernelGGL(transformer_kernel, dim3(B), dim3(NT), 0, stream,
                     tokens, emb, wbuf, bq, bk, bv, b1, b2, lng, lnb, out);
}

// Round 20
// 1661.063 us; speedup vs baseline: 1.1577x; 1.0007x over previous
//
#include <hip/hip_runtime.h>
#include <hip/hip_bf16.h>
#include <math.h>

#define LQ 50
#define DD 200
#define NBLK 3
#define NT 1024
#define NW 16

#define KC 13          // k-chunks of 16 for 32x32 MFMA (208 >= 200)
#define NT32 7         // n-tiles of 32 (224 >= 200)
#define MAT_U (KC * NT32 * 128)  // s16x8 units per matrix

#define APS 408   // pair-buffer row stride (shorts)
#define VTS 72    // v_T row stride (shorts)
#define PS  136   // P row stride (shorts)
#define SS  66    // S row stride (floats)

#define NEGC (-4294967295.0f)
#define SCALE 0.07071067811865475f

typedef __attribute__((ext_vector_type(4)))  float f32x4;
typedef __attribute__((ext_vector_type(16))) float f32x16;
typedef __attribute__((ext_vector_type(8)))  short s16x8;

__device__ __forceinline__ unsigned short bf16_rne(float x) {
  unsigned u = __float_as_uint(x);
  unsigned r = u + 0x7FFF + ((u >> 16) & 1);
  return (unsigned short)(r >> 16);
}
__device__ __forceinline__ float bf16_f(unsigned short h) {
  return __uint_as_float((unsigned)h << 16);
}
__device__ __forceinline__ void splitf(float x, short& h, short& l) {
  __hip_bfloat16 bh = __float2bfloat16(x);
  float hf = __bfloat162float(bh);
  __hip_bfloat16 bl = __float2bfloat16(x - hf);
  h = (short)__builtin_bit_cast(unsigned short, bh);
  l = (short)__builtin_bit_cast(unsigned short, bl);
}
__device__ __forceinline__ unsigned short bfbits(float x) {
  __hip_bfloat16 bh = __float2bfloat16(x);
  return __builtin_bit_cast(unsigned short, bh);
}
__device__ __forceinline__ float joinf(short h, short l) {
  return __bfloat162float(__builtin_bit_cast(__hip_bfloat16, (unsigned short)h)) +
         __bfloat162float(__builtin_bit_cast(__hip_bfloat16, (unsigned short)l));
}

__device__ __forceinline__ float wave_sum(float v) {
  #pragma unroll
  for (int off = 32; off > 0; off >>= 1) v += __shfl_xor(v, off, 64);
  return v;
}
__device__ __forceinline__ float wave_max(float v) {
  #pragma unroll
  for (int off = 32; off > 0; off >>= 1) v = fmaxf(v, __shfl_xor(v, off, 64));
  return v;
}

// ---- pre-swizzle: W f32 [DD][DD] -> bf16 hi/lo fragments for 32x32x16 ----
// chunk (mat, kc, nt): lane l covers n = nt*32+(l&31), k = kc*16+(l>>5)*8+j
__global__ __launch_bounds__(64)
void swizzle_w(const float* __restrict__ Wq, const float* __restrict__ Wk,
               const float* __restrict__ Wv, const float* __restrict__ W1,
               const float* __restrict__ W2, unsigned short* __restrict__ wbuf)
{
  int t = blockIdx.x;             // 15*KC*NT32
  int nt = t % NT32; t /= NT32;
  int kc = t % KC;  t /= KC;
  int mat = t;
  int layer = mat / 5, which = mat % 5;
  const float* W;
  switch (which) {
    case 0: W = Wq; break;
    case 1: W = Wk; break;
    case 2: W = Wv; break;
    case 3: W = W1; break;
    default: W = W2; break;
  }
  W += (size_t)layer * DD * DD;

  const int l = threadIdx.x;
  const int n = nt * 32 + (l & 31);
  const int kb = kc * 16 + (l >> 5) * 8;
  s16x8 vh, vl;
  #pragma unroll
  for (int j = 0; j < 8; ++j) {
    int k = kb + j;
    float w = (k < DD && n < DD) ? W[k * DD + n] : 0.0f;
    unsigned short h = bf16_rne(w);
    unsigned short lo = bf16_rne(w - bf16_f(h));
    vh[j] = (short)h;
    vl[j] = (short)lo;
  }
  size_t base = ((size_t)((mat * KC + kc) * NT32 + nt)) * 1024 + l * 8;
  *(s16x8*)(wbuf + base)       = vh;
  *(s16x8*)(wbuf + base + 512) = vl;
}

// ---- 32x32 matmul, C^T (A=W, B=x pair), pair dst with relu. nt in 0..6 ----
__device__ __forceinline__ void mm32_ct_pair(
    const short* __restrict__ srcp, const s16x8* __restrict__ wt,
    const float* __restrict__ bias, short* __restrict__ dstp, int nt, int lane)
{
  const int h = lane >> 5, l31 = lane & 31;
  f32x16 acc0 = (f32x16)0.f, acc1 = (f32x16)0.f;
  int r1 = 32 + l31; if (r1 >= LQ) r1 = 0;
  const short* arow0 = srcp + l31 * APS;       // rows 0..31 all valid
  const short* arow1 = srcp + r1 * APS;

  #pragma unroll 1
  for (int kc = 0; kc < KC; ++kc) {
    const s16x8* wp = wt + (size_t)(kc * NT32 + nt) * 128 + lane;
    s16x8 wh = wp[0], wl = wp[64];
    const int ch = 2 * kc + h;
    const bool ok = (ch < 25);
    {
      s16x8 ah = (s16x8)0, al = (s16x8)0;
      if (ok) { const short* p = arow0 + ch * 16; ah = *(const s16x8*)p; al = *(const s16x8*)(p + 8); }
      acc0 = __builtin_amdgcn_mfma_f32_32x32x16_bf16(wh, ah, acc0, 0, 0, 0);
      acc0 = __builtin_amdgcn_mfma_f32_32x32x16_bf16(wh, al, acc0, 0, 0, 0);
      acc0 = __builtin_amdgcn_mfma_f32_32x32x16_bf16(wl, ah, acc0, 0, 0, 0);
    }
    {
      s16x8 ah = (s16x8)0, al = (s16x8)0;
      if (ok) { const short* p = arow1 + ch * 16; ah = *(const s16x8*)p; al = *(const s16x8*)(p + 8); }
      acc1 = __builtin_amdgcn_mfma_f32_32x32x16_bf16(wh, ah, acc1, 0, 0, 0);
      acc1 = __builtin_amdgcn_mfma_f32_32x32x16_bf16(wh, al, acc1, 0, 0, 0);
      acc1 = __builtin_amdgcn_mfma_f32_32x32x16_bf16(wl, ah, acc1, 0, 0, 0);
    }
  }

  // C^T: lane holds n_local = (reg&3)+8*(reg>>2)+4h for r = rt*32 + l31
  #pragma unroll
  for (int rt = 0; rt < 2; ++rt) {
    const int r = rt * 32 + l31;
    if (r < LQ) {
      #pragma unroll
      for (int q2 = 0; q2 < 4; ++q2) {
        const int nb = nt * 32 + 8 * q2 + 4 * h;
        if (nb + 3 < DD) {
          float4 bv = *(const float4*)(bias + nb);
          float v0 = fmaxf((rt ? acc1[q2*4+0] : acc0[q2*4+0]) + bv.x, 0.f);
          float v1 = fmaxf((rt ? acc1[q2*4+1] : acc0[q2*4+1]) + bv.y, 0.f);
          float v2 = fmaxf((rt ? acc1[q2*4+2] : acc0[q2*4+2]) + bv.z, 0.f);
          float v3 = fmaxf((rt ? acc1[q2*4+3] : acc0[q2*4+3]) + bv.w, 0.f);
          short h0,l0,h1,l1,h2,l2,h3,l3;
          splitf(v0,h0,l0); splitf(v1,h1,l1); splitf(v2,h2,l2); splitf(v3,h3,l3);
          uint2 ph, pl;
          ph.x = (unsigned short)h0 | ((unsigned)(unsigned short)h1 << 16);
          ph.y = (unsigned short)h2 | ((unsigned)(unsigned short)h3 << 16);
          pl.x = (unsigned short)l0 | ((unsigned)(unsigned short)l1 << 16);
          pl.y = (unsigned short)l2 | ((unsigned)(unsigned short)l3 << 16);
          short* base = dstp + r * APS + (nb >> 3) * 16 + (nb & 7);
          *(uint2*)base = ph;
          *(uint2*)(base + 8) = pl;
        }
      }
    }
  }
}

// ---- 32x32 V projection (A=x pair, B=W), hi-only transposed dst ----
__device__ __forceinline__ void mm32_v(
    const short* __restrict__ srcp, const s16x8* __restrict__ wt,
    const float* __restrict__ bias, short* __restrict__ vtp, int nt, int lane)
{
  const int h = lane >> 5, l31 = lane & 31;
  f32x16 acc0 = (f32x16)0.f, acc1 = (f32x16)0.f;
  int r1 = 32 + l31; if (r1 >= LQ) r1 = 0;
  const short* arow0 = srcp + l31 * APS;
  const short* arow1 = srcp + r1 * APS;

  #pragma unroll 1
  for (int kc = 0; kc < KC; ++kc) {
    const s16x8* wp = wt + (size_t)(kc * NT32 + nt) * 128 + lane;
    s16x8 wh = wp[0], wl = wp[64];
    const int ch = 2 * kc + h;
    const bool ok = (ch < 25);
    {
      s16x8 ah = (s16x8)0, al = (s16x8)0;
      if (ok) { const short* p = arow0 + ch * 16; ah = *(const s16x8*)p; al = *(const s16x8*)(p + 8); }
      acc0 = __builtin_amdgcn_mfma_f32_32x32x16_bf16(ah, wh, acc0, 0, 0, 0);
      acc0 = __builtin_amdgcn_mfma_f32_32x32x16_bf16(al, wh, acc0, 0, 0, 0);
      acc0 = __builtin_amdgcn_mfma_f32_32x32x16_bf16(ah, wl, acc0, 0, 0, 0);
    }
    {
      s16x8 ah = (s16x8)0, al = (s16x8)0;
      if (ok) { const short* p = arow1 + ch * 16; ah = *(const s16x8*)p; al = *(const s16x8*)(p + 8); }
      acc1 = __builtin_amdgcn_mfma_f32_32x32x16_bf16(ah, wh, acc1, 0, 0, 0);
      acc1 = __builtin_amdgcn_mfma_f32_32x32x16_bf16(al, wh, acc1, 0, 0, 0);
      acc1 = __builtin_amdgcn_mfma_f32_32x32x16_bf16(ah, wl, acc1, 0, 0, 0);
    }
  }

  // C: lane holds d = nt*32 + l31 (col), r_local = (reg&3)+8*(reg>>2)+4h + 32*mt
  const int d = nt * 32 + l31;
  if (d < DD) {
    const float bvs = bias[d];
    #pragma unroll
    for (int mt2 = 0; mt2 < 2; ++mt2) {
      #pragma unroll
      for (int q2 = 0; q2 < 4; ++q2) {
        const int rb = mt2 * 32 + 8 * q2 + 4 * h;
        float vv[4];
        #pragma unroll
        for (int e = 0; e < 4; ++e) {
          const int r = rb + e;
          float v = (mt2 ? acc1[q2*4+e] : acc0[q2*4+e]) + bvs;
          vv[e] = (r < LQ) ? fmaxf(v, 0.f) : 0.f;
        }
        uint2 pk;
        pk.x = (unsigned)bfbits(vv[0]) | ((unsigned)bfbits(vv[1]) << 16);
        pk.y = (unsigned)bfbits(vv[2]) | ((unsigned)bfbits(vv[3]) << 16);
        *(uint2*)(vtp + d * VTS + (rb >> 3) * 8 + (rb & 7)) = pk;
      }
    }
  }
}

// ---- 32x32 W1: C^T, pair-src (3-term), HI-ONLY pair dst, relu, prefetch ----
__device__ __forceinline__ void mm32_w1(
    const short* __restrict__ srcp, const s16x8* __restrict__ wt,
    const float* __restrict__ bias, short* __restrict__ dstp,
    int nt, int rt, int lane)
{
  const int h = lane >> 5, l31 = lane & 31;
  f32x16 acc = (f32x16)0.f;
  int r = rt * 32 + l31;
  int rr = (r >= LQ) ? 0 : r;
  const short* arow = srcp + rr * APS;

  const s16x8* wp = wt + (size_t)nt * 128 + lane;
  s16x8 wh = wp[0], wl = wp[64];
  #pragma unroll 1
  for (int kc = 0; kc < KC; ++kc) {
    s16x8 nh = (s16x8)0, nl = (s16x8)0;
    if (kc + 1 < KC) {
      const s16x8* np = wt + (size_t)((kc + 1) * NT32 + nt) * 128 + lane;
      nh = np[0]; nl = np[64];
    }
    const int ch = 2 * kc + h;
    s16x8 ah = (s16x8)0, al = (s16x8)0;
    if (ch < 25) { const short* p = arow + ch * 16; ah = *(const s16x8*)p; al = *(const s16x8*)(p + 8); }
    acc = __builtin_amdgcn_mfma_f32_32x32x16_bf16(wh, ah, acc, 0, 0, 0);
    acc = __builtin_amdgcn_mfma_f32_32x32x16_bf16(wh, al, acc, 0, 0, 0);
    acc = __builtin_amdgcn_mfma_f32_32x32x16_bf16(wl, ah, acc, 0, 0, 0);
    wh = nh; wl = nl;
  }

  if (r < LQ) {
    #pragma unroll
    for (int q2 = 0; q2 < 4; ++q2) {
      const int nb = nt * 32 + 8 * q2 + 4 * h;
      if (nb + 3 < DD) {
        float4 bv = *(const float4*)(bias + nb);
        float v0 = fmaxf(acc[q2*4+0] + bv.x, 0.f);
        float v1 = fmaxf(acc[q2*4+1] + bv.y, 0.f);
        float v2 = fmaxf(acc[q2*4+2] + bv.z, 0.f);
        float v3 = fmaxf(acc[q2*4+3] + bv.w, 0.f);
        uint2 ph;
        ph.x = (unsigned)bfbits(v0) | ((unsigned)bfbits(v1) << 16);
        ph.y = (unsigned)bfbits(v2) | ((unsigned)bfbits(v3) << 16);
        *(uint2*)(dstp + r * APS + (nb >> 3) * 16 + (nb & 7)) = ph;   // hi only
      }
    }
  }
}

// ---- 32x32 W2: C^T, HI-only src (2-term), f32 dst, no relu, prefetch ----
__device__ __forceinline__ void mm32_w2(
    const short* __restrict__ srcp, const s16x8* __restrict__ wt,
    const float* __restrict__ bias, float* __restrict__ dstf,
    int nt, int rt, int lane)
{
  const int h = lane >> 5, l31 = lane & 31;
  f32x16 acc = (f32x16)0.f;
  int r = rt * 32 + l31;
  int rr = (r >= LQ) ? 0 : r;
  const short* arow = srcp + rr * APS;

  const s16x8* wp = wt + (size_t)nt * 128 + lane;
  s16x8 wh = wp[0], wl = wp[64];
  #pragma unroll 1
  for (int kc = 0; kc < KC; ++kc) {
    s16x8 nh = (s16x8)0, nl = (s16x8)0;
    if (kc + 1 < KC) {
      const s16x8* np = wt + (size_t)((kc + 1) * NT32 + nt) * 128 + lane;
      nh = np[0]; nl = np[64];
    }
    const int ch = 2 * kc + h;
    s16x8 ah = (s16x8)0;
    if (ch < 25) ah = *(const s16x8*)(arow + ch * 16);   // hi only
    acc = __builtin_amdgcn_mfma_f32_32x32x16_bf16(wh, ah, acc, 0, 0, 0);
    acc = __builtin_amdgcn_mfma_f32_32x32x16_bf16(wl, ah, acc, 0, 0, 0);
    wh = nh; wl = nl;
  }

  if (r < LQ) {
    #pragma unroll
    for (int q2 = 0; q2 < 4; ++q2) {
      const int d0 = nt * 32 + 8 * q2 + 4 * h;
      if (d0 + 3 < DD) {
        float4 bv = *(const float4*)(bias + d0);
        float4 w4;
        w4.x = acc[q2*4+0] + bv.x; w4.y = acc[q2*4+1] + bv.y;
        w4.z = acc[q2*4+2] + bv.z; w4.w = acc[q2*4+3] + bv.w;
        *(float4*)(dstf + r * DD + d0) = w4;
      }
    }
  }
}

__global__ __launch_bounds__(NT)
void transformer_kernel(const int* __restrict__ tokens,
                        const float* __restrict__ emb,
                        const unsigned short* __restrict__ wbuf,
                        const float* __restrict__ bq, const float* __restrict__ bk,
                        const float* __restrict__ bv, const float* __restrict__ b1,
                        const float* __restrict__ b2,
                        const float* __restrict__ lng, const float* __restrict__ lnb,
                        float* __restrict__ out)
{
  __shared__ __align__(16) short xs_p[LQ * APS];
  __shared__ __align__(16) short q_p [LQ * APS];
  __shared__ __align__(16) short k_p [LQ * APS];
  __shared__ __align__(16) short vt_p[DD * VTS];
  __shared__ float rowsum[52];

  float* Sf  = (float*)q_p;          // S f32 [50][66]
  short* Pp  = q_p + 8192;           // P hi-only [50][PS]
  float* h2f = (float*)k_p;          // h2 f32 [50][200]

  const int b    = blockIdx.x;
  const int tid  = threadIdx.x;
  const int lane = tid & 63;
  const int wv   = tid >> 6;
  const int g    = lane >> 4, c = lane & 15;   // 16x16 frag coords (phases 3-6)

  // ---- embedding gather -> xs pair
  for (int o = tid; o < LQ * 25; o += NT) {
    int r = o / 25, ch = o % 25;
    int tok = tokens[b * LQ + r];
    const float* ep = emb + (size_t)tok * DD + ch * 8;
    float4 a0 = *(const float4*)ep;
    float4 a1 = *(const float4*)(ep + 4);
    float xv[8] = {a0.x, a0.y, a0.z, a0.w, a1.x, a1.y, a1.z, a1.w};
    s16x8 hh, ll;
    #pragma unroll
    for (int j = 0; j < 8; ++j) { short h, l; splitf(xv[j], h, l); hh[j] = h; ll[j] = l; }
    short* dp = xs_p + r * APS + ch * 16;
    *(s16x8*)dp = hh;
    *(s16x8*)(dp + 8) = ll;
  }
  __syncthreads();

  for (int layer = 0; layer < NBLK; ++layer) {
    const s16x8* wq  = (const s16x8*)wbuf + (size_t)(layer * 5 + 0) * MAT_U;
    const s16x8* wk  = (const s16x8*)wbuf + (size_t)(layer * 5 + 1) * MAT_U;
    const s16x8* wvv = (const s16x8*)wbuf + (size_t)(layer * 5 + 2) * MAT_U;
    const s16x8* w1  = (const s16x8*)wbuf + (size_t)(layer * 5 + 3) * MAT_U;
    const s16x8* w2  = (const s16x8*)wbuf + (size_t)(layer * 5 + 4) * MAT_U;
    const float* bql = bq + layer * DD;
    const float* bkl = bk + layer * DD;
    const float* bvl = bv + layer * DD;
    const float* b1l = b1 + layer * DD;
    const float* b2l = b2 + layer * DD;
    const float* gl  = lng + layer * DD;
    const float* bl  = lnb + layer * DD;

    if (layer == 0) {
      for (int r = wv; r < LQ; r += NW) {
        float s = 0.f;
        #pragma unroll
        for (int t = 0; t < 4; ++t) {
          int cc = lane + 64 * t;
          if (cc < DD) {
            const short* p = xs_p + r * APS + (cc >> 3) * 16 + (cc & 7);
            s += joinf(p[0], p[8]);
          }
        }
        s = wave_sum(s);
        if (lane == 0) rowsum[r] = s;
      }
    }

    // ---- phase 2: Q (waves 0-6) || K (waves 8-14)
    if (wv < 7)                   mm32_ct_pair(xs_p, wq, bql, q_p, wv, lane);
    else if (wv >= 8 && wv < 15)  mm32_ct_pair(xs_p, wk, bkl, k_p, wv - 8, lane);
    __syncthreads();

    // ---- phase 3: S = Q K^T (waves 8-15, 16x16)  ||  V projection (waves 0-6)
    f32x4 s0 = (f32x4)0.f, s1 = (f32x4)0.f;
    if (wv >= 8) {
      const int w8 = wv - 8;
      const int mt = w8 >> 1;
      const int nk0 = (w8 & 1) * 2;
      int qr = mt * 16 + c;          if (qr >= LQ) qr = 0;
      int kj0 = nk0 * 16 + c;        if (kj0 >= LQ) kj0 = 0;
      int kj1 = (nk0 + 1) * 16 + c;  if (kj1 >= LQ) kj1 = 0;
      const short* qrow = q_p + qr * APS;
      const short* k0r  = k_p + kj0 * APS;
      const short* k1r  = k_p + kj1 * APS;
      #pragma unroll 1
      for (int kt = 0; kt < 7; ++kt) {
        const int ch = kt * 4 + g;
        s16x8 qh = (s16x8)0, ql = (s16x8)0;
        s16x8 kh0 = (s16x8)0, kl0 = (s16x8)0, kh1 = (s16x8)0, kl1 = (s16x8)0;
        if (ch < 25) {
          qh  = *(const s16x8*)(qrow + ch * 16); ql  = *(const s16x8*)(qrow + ch * 16 + 8);
          kh0 = *(const s16x8*)(k0r + ch * 16);  kl0 = *(const s16x8*)(k0r + ch * 16 + 8);
          kh1 = *(const s16x8*)(k1r + ch * 16);  kl1 = *(const s16x8*)(k1r + ch * 16 + 8);
        }
        s0 = __builtin_amdgcn_mfma_f32_16x16x32_bf16(qh, kh0, s0, 0, 0, 0);
        s0 = __builtin_amdgcn_mfma_f32_16x16x32_bf16(ql, kh0, s0, 0, 0, 0);
        s0 = __builtin_amdgcn_mfma_f32_16x16x32_bf16(qh, kl0, s0, 0, 0, 0);
        s1 = __builtin_amdgcn_mfma_f32_16x16x32_bf16(qh, kh1, s1, 0, 0, 0);
        s1 = __builtin_amdgcn_mfma_f32_16x16x32_bf16(ql, kh1, s1, 0, 0, 0);
        s1 = __builtin_amdgcn_mfma_f32_16x16x32_bf16(qh, kl1, s1, 0, 0, 0);
      }
    } else if (wv < 7) {
      mm32_v(xs_p, wvv, bvl, vt_p, wv, lane);
    }
    __syncthreads();   // all q_p reads done -> S may overwrite

    // ---- phase 4: write S (scaled + key-masked) into Sf
    if (wv >= 8) {
      const int w8 = wv - 8;
      const int mt = w8 >> 1;
      const int nk0 = (w8 & 1) * 2;
      #pragma unroll
      for (int t = 0; t < 2; ++t) {
        const int j = (nk0 + t) * 16 + c;
        const f32x4 sa = t ? s1 : s0;
        const bool km = (j < LQ) && (rowsum[j] != 0.0f);
        #pragma unroll
        for (int q = 0; q < 4; ++q) {
          const int qi = mt * 16 + g * 4 + q;
          if (qi < LQ) Sf[qi * SS + j] = km ? sa[q] * SCALE : NEGC;
        }
      }
    }
    __syncthreads();

    // ---- phase 5: softmax rows -> P (hi only)
    for (int r = wv; r < LQ; r += NW) {
      float sm = -INFINITY;
      if (lane < LQ) sm = Sf[r * SS + lane];
      float m = wave_max(sm);
      float e = (lane < LQ) ? __expf(sm - m) : 0.0f;
      float ssum = wave_sum(e);
      float qm = (rowsum[r] == 0.0f) ? 0.0f : 1.0f;
      float a = e / ssum * qm;
      Pp[r * PS + (lane >> 3) * 16 + (lane & 7)] = (short)bfbits(a);
    }
    __syncthreads();

    // ---- phase 6: out^T = V^T @ P^T (P hi-only); residual RMW into xs pair
    if (wv < 13) {
      const int mt = wv;
      f32x4 pa[4];
      #pragma unroll
      for (int nq = 0; nq < 4; ++nq) pa[nq] = (f32x4)0.f;
      int vr = mt * 16 + c; if (vr >= DD) vr = 0;
      const short* vrow = vt_p + vr * VTS;
      #pragma unroll
      for (int kt = 0; kt < 2; ++kt) {
        s16x8 vh = *(const s16x8*)(vrow + (kt * 4 + g) * 8);
        #pragma unroll
        for (int nq = 0; nq < 4; ++nq) {
          int pr = nq * 16 + c; if (pr >= LQ) pr = 0;
          s16x8 pbh = *(const s16x8*)(Pp + pr * PS + (kt * 4 + g) * 16);
          pa[nq] = __builtin_amdgcn_mfma_f32_16x16x32_bf16(vh, pbh, pa[nq], 0, 0, 0);
        }
      }
      const int d0 = mt * 16 + g * 4;
      if (d0 + 3 < DD) {
        #pragma unroll
        for (int nq = 0; nq < 4; ++nq) {
          const int qq = nq * 16 + c;
          if (qq < LQ) {
            short* base = xs_p + qq * APS + (d0 >> 3) * 16 + (d0 & 7);
            uint2 ph = *(const uint2*)base;
            uint2 pl = *(const uint2*)(base + 8);
            float f0 = joinf((short)(ph.x & 0xFFFF), (short)(pl.x & 0xFFFF)) + pa[nq][0];
            float f1 = joinf((short)(ph.x >> 16),    (short)(pl.x >> 16))    + pa[nq][1];
            float f2 = joinf((short)(ph.y & 0xFFFF), (short)(pl.y & 0xFFFF)) + pa[nq][2];
            float f3 = joinf((short)(ph.y >> 16),    (short)(pl.y >> 16))    + pa[nq][3];
            short h0,l0,h1,l1,h2,l2,h3,l3;
            splitf(f0,h0,l0); splitf(f1,h1,l1); splitf(f2,h2,l2); splitf(f3,h3,l3);
            ph.x = (unsigned short)h0 | ((unsigned)(unsigned short)h1 << 16);
            ph.y = (unsigned short)h2 | ((unsigned)(unsigned short)h3 << 16);
            pl.x = (unsigned short)l0 | ((unsigned)(unsigned short)l1 << 16);
            pl.y = (unsigned short)l2 | ((unsigned)(unsigned short)l3 << 16);
            *(uint2*)base = ph;
            *(uint2*)(base + 8) = pl;
          }
        }
      }
    }
    __syncthreads();

    // ---- phase 7: W1 -> h1 (hi-only) in q_p  (14 waves)
    if (wv < 14) mm32_w1(xs_p, w1, b1l, q_p, wv >> 1, wv & 1, lane);
    __syncthreads();
    // ---- phase 8: W2 -> h2 f32 in k_p  (14 waves, h1 hi-only src)
    if (wv < 14) mm32_w2(q_p, w2, b2l, h2f, wv >> 1, wv & 1, lane);
    __syncthreads();

    // ---- phase 9: LayerNorm + residual -> xs pair; next-layer rowsum
    for (int r = wv; r < LQ; r += NW) {
      float hv[4];
      #pragma unroll
      for (int t = 0; t < 4; ++t) {
        int cc = lane + 64 * t;
        hv[t] = (cc < DD) ? h2f[r * DD + cc] : 0.f;
      }
      float mu = wave_sum(hv[0] + hv[1] + hv[2] + hv[3]) * (1.0f / 200.0f);
      float d0 = hv[0] - mu, d1 = hv[1] - mu, d2 = hv[2] - mu;
      float d3 = (lane + 192 < DD) ? (hv[3] - mu) : 0.f;
      float var = wave_sum(d0 * d0 + d1 * d1 + d2 * d2 + d3 * d3) * (1.0f / 200.0f);
      float inv = 1.0f / sqrtf(var + 1e-8f);
      float dd4[4] = {d0, d1, d2, d3};
      float rs = 0.f;
      #pragma unroll
      for (int t = 0; t < 4; ++t) {
        int cc = lane + 64 * t;
        if (cc < DD) {
          short* hp = xs_p + r * APS + (cc >> 3) * 16 + (cc & 7);
          float nv = dd4[t] * inv * gl[cc] + bl[cc] + joinf(hp[0], hp[8]);
          rs += nv;
          short h, l; splitf(nv, h, l);
          hp[0] = h; hp[8] = l;
        }
      }
      rs = wave_sum(rs);
      if (lane == 0) rowsum[r] = rs;
    }
    __syncthreads();
  }

  // ---- write result
  for (int o = tid; o < LQ * 25; o += NT) {
    int r = o / 25, ch = o % 25;
    const short* sp = xs_p + r * APS + ch * 16;
    s16x8 hh = *(const s16x8*)sp;
    s16x8 ll = *(const s16x8*)(sp + 8);
    float4 o0, o1;
    o0.x = joinf(hh[0], ll[0]); o0.y = joinf(hh[1], ll[1]);
    o0.z = joinf(hh[2], ll[2]); o0.w = joinf(hh[3], ll[3]);
    o1.x = joinf(hh[4], ll[4]); o1.y = joinf(hh[5], ll[5]);
    o1.z = joinf(hh[6], ll[6]); o1.w = joinf(hh[7], ll[7]);
    float* op = out + ((size_t)b * LQ + r) * DD + ch * 8;
    *(float4*)op = o0;
    *(float4*)(op + 4) = o1;
  }
}

extern "C" void kernel_launch(void* const* d_in, const int* in_sizes, int n_in,
                              void* d_out, int out_size, void* d_ws, size_t ws_size,
                              hipStream_t stream) {
  const int*   tokens = (const int*)  d_in[0];
  const float* emb    = (const float*)d_in[1];
  const float* Wq     = (const float*)d_in[2];
  const float* bq     = (const float*)d_in[3];
  const float* Wk     = (const float*)d_in[4];
  const float* bk     = (const float*)d_in[5];
  const float* Wv     = (const float*)d_in[6];
  const float* bv     = (const float*)d_in[7];
  const float* W1     = (const float*)d_in[8];
  const float* b1     = (const float*)d_in[9];
  const float* W2     = (const float*)d_in[10];
  const float* b2     = (const float*)d_in[11];
  const float* lng    = (const float*)d_in[12];
  const float* lnb    = (const float*)d_in[13];
  float* out = (float*)d_out;
  unsigned short* wbuf = (unsigned short*)d_ws;

  hipLaunchKernelGGL(swizzle_w, dim3(15 * KC * NT32), dim3(64), 0, stream,
                     Wq, Wk, Wv, W1, W2, wbuf);

  const int B = in_sizes[0] / LQ;   // 4096
  hipLaunchKernelGGL(transformer_kernel, dim3(B), dim3(NT), 0, stream,
                     tokens, emb, wbuf, bq, bk, bv, b1, b2, lng, lnb, out);
}